// Round 15
// baseline (228.240 us; speedup 1.0000x reference)
//
#include <hip/hip_runtime.h>
#include <hip/hip_bf16.h>

// ---------------------------------------------------------------------------
// CrossFormerBlock on MI355X (gfx950)
// B=1 D=16 H=32 W=32 T=4 C=128, G=4, NH=8, HD=16, NW=256 windows, N=256 tok/win
// R15: (a) GEMM reverted to R13 BK=64 (R14's BK=128 -> 16-way LDS conflicts +
// occupancy drop, regressed). (b) NEW fused MLP kernel: fc1+GELU+fc2 in one
// kernel — GEMM1's D^T fragment IS GEMM2's A-operand fragment (attention
// trick), so h1 never leaves registers; gbuf (128MB HBM round-trip) deleted.
// ---------------------------------------------------------------------------

typedef __attribute__((ext_vector_type(8))) short  s16x8;
typedef __attribute__((ext_vector_type(4))) short  s16x4;
typedef __attribute__((ext_vector_type(4))) float  f32x4;
typedef __attribute__((ext_vector_type(8))) _Float16 f16x8;
typedef __attribute__((ext_vector_type(4))) _Float16 f16x4;

#define CC    128
#define NWIN  256
#define TOKS  65536            // total tokens = D*H*W*T
#define SCALE 0.25f
#define LNEPS 1e-5f
// padded spatial geometry for conv
#define PD 18
#define PH 34
#define PW 34
#define PSITES (PD*PH*PW)                // 20808
#define Y1P_SHORTS ((size_t)PSITES*512)  // *4t*128c

__device__ __forceinline__ float b2f(short s) {
  union { unsigned u; float f; } c; c.u = ((unsigned)(unsigned short)s) << 16; return c.f;
}
__device__ __forceinline__ short f2b(float f) {
  __hip_bfloat16 h = __float2bfloat16(f);
  return *reinterpret_cast<short*>(&h);
}
__device__ __forceinline__ float fast_gelu(float x) {
  float u = 1.595769122f * x * fmaf(0.044715f, x*x, 1.0f);
  return x / (1.0f + __expf(-u));
}

__device__ __forceinline__ f32x4 mfma16x16x16_bf16(s16x4 a, s16x4 b, f32x4 c) {
#if __has_builtin(__builtin_amdgcn_mfma_f32_16x16x16_bf16)
  return __builtin_amdgcn_mfma_f32_16x16x16_bf16(a, b, c, 0, 0, 0);
#elif __has_builtin(__builtin_amdgcn_mfma_f32_16x16x16bf16_1k)
  return __builtin_amdgcn_mfma_f32_16x16x16bf16_1k(a, b, c, 0, 0, 0);
#else
  f32x4 d;
  asm("v_mfma_f32_16x16x16_bf16 %0, %1, %2, %3" : "=v"(d) : "v"(a), "v"(b), "v"(c));
  return d;
#endif
}

// async global->LDS, 16B per lane; lds base wave-uniform (HW appends lane*16).
__device__ __forceinline__ void gload16(const short* g, short* l) {
  __builtin_amdgcn_global_load_lds(
      (const __attribute__((address_space(1))) void*)g,
      (__attribute__((address_space(3))) void*)l, 16, 0, 0);
}

// ---------------------------------------------------------------------------
// Kernel 0: weight prep
// ---------------------------------------------------------------------------
__global__ void prep_kernel(const float* __restrict__ qkv_w, const float* __restrict__ proj_w,
                            const float* __restrict__ fc1_w, const float* __restrict__ fc2_w,
                            const float* __restrict__ conv_w,
                            __hip_bfloat16* wq, __hip_bfloat16* wp,
                            __hip_bfloat16* w1, __hip_bfloat16* w2, float* cwT) {
  int idx = blockIdx.x * 256 + threadIdx.x;
  if (idx < 49152) {
    wq[idx] = __float2bfloat16(qkv_w[idx]);
  } else if (idx < 65536) {
    wp[idx - 49152] = __float2bfloat16(proj_w[idx - 49152]);
  } else if (idx < 131072) {
    w1[idx - 65536] = __float2bfloat16(fc1_w[idx - 65536]);
  } else if (idx < 196608) {
    w2[idx - 131072] = __float2bfloat16(fc2_w[idx - 131072]);
  } else if (idx < 196608 + 27*128) {
    int j = idx - 196608;
    int tap = j >> 7, c = j & 127;
    cwT[tap*128 + c] = conv_w[c*27 + tap];   // (C,1,3,3,3) -> (27,C)
  }
}

// ---------------------------------------------------------------------------
// Kernel: zero only the BORDER sites of the padded y1 buffer (4424 sites).
// ---------------------------------------------------------------------------
__global__ __launch_bounds__(256) void border_zero_kernel(short* __restrict__ y1p) {
  int idx = blockIdx.x*256 + threadIdx.x;
  if (idx >= PSITES*64) return;
  int site = idx >> 6;
  int w = site % PW, hh = (site / PW) % PH, d = site / (PW*PH);
  if (d != 0 && d != PD-1 && hh != 0 && hh != PH-1 && w != 0 && w != PW-1) return;
  *(s16x8*)&y1p[(size_t)site*512 + (idx & 63)*8] = (s16x8)0;
}

// ---------------------------------------------------------------------------
// Kernel 1: LN1 + positional/temporal embed -> window-token layout bf16
// ---------------------------------------------------------------------------
__global__ __launch_bounds__(256) void ln1_pe_kernel(
    const float* __restrict__ x, const float* __restrict__ g, const float* __restrict__ b,
    const float* __restrict__ pos, const float* __restrict__ te,
    __hip_bfloat16* __restrict__ hb) {
  int wv = threadIdx.x >> 6, lane = threadIdx.x & 63;
  int tk = blockIdx.x * 4 + wv;                 // tk = wid*256 + n
  int wid = tk >> 8, n = tk & 255;
  int t = n >> 6, gd = (n >> 4) & 3, gh = (n >> 2) & 3, gw = n & 3;
  int wd = wid >> 6, wh = (wid >> 3) & 7, ww = wid & 7;
  int d = wd*4 + gd, h = wh*4 + gh, w = ww*4 + gw;
  size_t xoff = ((size_t)((d*32 + h)*32 + w)*4 + t) * CC;
  float v0 = x[xoff + lane], v1 = x[xoff + lane + 64];
  float s = v0 + v1, sq = v0*v0 + v1*v1;
  for (int m = 32; m; m >>= 1) { s += __shfl_xor(s, m); sq += __shfl_xor(sq, m); }
  float mean = s * (1.f/128.f);
  float var  = sq * (1.f/128.f) - mean*mean;
  float rstd = rsqrtf(var + LNEPS);
  int pb = ((gd*4 + gh)*4 + gw) * CC, tb = t * CC;
  float h0 = (v0 - mean)*rstd*g[lane]    + b[lane]    + pos[pb + lane]    + te[tb + lane];
  float h1 = (v1 - mean)*rstd*g[lane+64] + b[lane+64] + pos[pb + lane+64] + te[tb + lane+64];
  hb[(size_t)tk*CC + lane]      = __float2bfloat16(h0);
  hb[(size_t)tk*CC + lane + 64] = __float2bfloat16(h1);
}

// ---------------------------------------------------------------------------
// GEMM template (R13 version): 128x128 tile, BK=64, 4 waves, compile-time K.
// Staging: global_load_lds width=16, LINEAR LDS [128][64].
// MODE 0: qkv split; MODE 1: proj -> PADDED spatial scatter bf16.
// ---------------------------------------------------------------------------
template <int MODE, int KK>
__global__ __launch_bounds__(256) void gemm_kernel(
    const short* __restrict__ Ag, const short* __restrict__ Wg,
    const float* __restrict__ bias,
    void* __restrict__ out0, const _Float16* __restrict__ resid) {
  __shared__ __align__(16) short As[128*64];
  __shared__ __align__(16) short Bs[128*64];
  const int tid = threadIdx.x;
  const int m0 = blockIdx.x * 128;
  const int n0 = blockIdx.y * 128;
  const int lane = tid & 63, wv = tid >> 6;
  const int wr = wv >> 1, wc = wv & 1;
  const int fr = lane & 15, kg = lane >> 4;

  f32x4 acc[4][4];
#pragma unroll
  for (int i = 0; i < 4; ++i)
#pragma unroll
    for (int j = 0; j < 4; ++j) acc[i][j] = (f32x4)0.f;

#pragma unroll
  for (int kc = 0; kc < KK; kc += 64) {
    __syncthreads();
#pragma unroll
    for (int i = 0; i < 4; ++i) {
      const int e = i*2048 + tid*8;          // short index in 128x64 tile
      const int row = e >> 6, col = e & 63;
      gload16(Ag + (size_t)(m0 + row)*KK + kc + col, &As[i*2048 + wv*512]);
      gload16(Wg + (size_t)(n0 + row)*KK + kc + col, &Bs[i*2048 + wv*512]);
    }
    __syncthreads();
#pragma unroll
    for (int ks = 0; ks < 2; ++ks) {
      s16x8 a[4], b[4];
#pragma unroll
      for (int i = 0; i < 4; ++i)
        a[i] = *(const s16x8*)&As[(wr*64 + i*16 + fr)*64 + ks*32 + kg*8];
#pragma unroll
      for (int j = 0; j < 4; ++j)
        b[j] = *(const s16x8*)&Bs[(wc*64 + j*16 + fr)*64 + ks*32 + kg*8];
#pragma unroll
      for (int i = 0; i < 4; ++i)
#pragma unroll
        for (int j = 0; j < 4; ++j)
          acc[i][j] = __builtin_amdgcn_mfma_f32_16x16x32_bf16(b[j], a[i], acc[i][j], 0, 0, 0);
    }
  }

  const int nbb = n0 + wc*64 + kg*4;
  f32x4 bj4[4];
#pragma unroll
  for (int j = 0; j < 4; ++j) bj4[j] = *(const f32x4*)&bias[nbb + j*16];

#pragma unroll
  for (int i = 0; i < 4; ++i) {
    const int m = m0 + wr*64 + i*16 + fr;
    if constexpr (MODE == 0) {
      short* qs = (short*)out0;
      const int sec = n0 >> 7;
      const float scl = (sec == 0) ? SCALE : 1.0f;
      const int wid = m >> 8, ntok = m & 255;
      const int rowbase = sec*8388608 + (wid*8)*4096 + ntok*16 + (nbb & 15);
#pragma unroll
      for (int j = 0; j < 4; ++j) {
        const int head = ((nbb + j*16) >> 4) & 7;
        f32x4 v = acc[i][j];
        s16x4 o;
        o[0] = f2b(fmaf(v[0], scl, bj4[j].x*scl));
        o[1] = f2b(fmaf(v[1], scl, bj4[j].y*scl));
        o[2] = f2b(fmaf(v[2], scl, bj4[j].z*scl));
        o[3] = f2b(fmaf(v[3], scl, bj4[j].w*scl));
        *(s16x4*)&qs[rowbase + head*4096] = o;
      }
    } else {
      short* y1o = (short*)out0;       // PADDED [18][34][34][4][128]
      const int wid = m >> 8, ntok = m & 255;
      const int t = ntok >> 6, gd = (ntok >> 4) & 3, gh = (ntok >> 2) & 3, gw = ntok & 3;
      const int wd = wid >> 6, wh = (wid >> 3) & 7, ww = wid & 7;
      const int sr = (((wd*4 + gd + 1)*PH + wh*4 + gh + 1)*PW + ww*4 + gw + 1)*4 + t;
      const int base = sr*CC + nbb;
#pragma unroll
      for (int j = 0; j < 4; ++j) {
        f32x4 v = acc[i][j];
        s16x4 o;
        o[0] = f2b(v[0] + bj4[j].x); o[1] = f2b(v[1] + bj4[j].y);
        o[2] = f2b(v[2] + bj4[j].z); o[3] = f2b(v[3] + bj4[j].w);
        *(s16x4*)&y1o[base + j*16] = o;
      }
    }
  }
}

// ---------------------------------------------------------------------------
// Kernel: FUSED MLP — out = gelu(h2 @ w1^T + b1) @ w2^T + b2 + resid.
// 512 blocks x 256 thr (4 waves; wave = 32 rows). Per slice s (128 of MLP_H):
// GEMM1 acc1[2][8] (16x16x32, A/Ws staged via gload16), then gelu+cvt feeds
// GEMM2 DIRECTLY: D^T fragment (lane holds h1[m=fr][k=kg*4+r], k-tile j) is
// exactly the 16x16x16 A-operand. w2 fragments read from global (L1/L2).
// h1 never touches memory. acc2 over 16 k-tiles = K=512.
// ---------------------------------------------------------------------------
__global__ __launch_bounds__(256) void mlp_kernel(
    const short* __restrict__ h2, const short* __restrict__ w1,
    const short* __restrict__ w2, const float* __restrict__ b1,
    const float* __restrict__ b2, const _Float16* __restrict__ resid,
    float* __restrict__ out) {
  __shared__ __align__(16) short As[128*128];
  __shared__ __align__(16) short Ws[128*128];
  const int tid = threadIdx.x;
  const int m0 = blockIdx.x * 128;
  const int lane = tid & 63, wv = tid >> 6;
  const int fr = lane & 15, kg = lane >> 4;

  // stage A (h2 tile [128][128]) once
#pragma unroll
  for (int i = 0; i < 8; ++i) {
    const int e = i*2048 + tid*8;
    const int row = e >> 7, col = e & 127;
    gload16(h2 + (size_t)(m0 + row)*128 + col, &As[i*2048 + wv*512]);
  }

  f32x4 acc2[2][8];
#pragma unroll
  for (int i = 0; i < 2; ++i)
#pragma unroll
    for (int c = 0; c < 8; ++c) acc2[i][c] = (f32x4)0.f;

#pragma unroll
  for (int s = 0; s < 4; ++s) {
    __syncthreads();                      // Ws reuse-safe (prev reads done)
#pragma unroll
    for (int i = 0; i < 8; ++i) {
      const int e = i*2048 + tid*8;
      const int row = e >> 7, col = e & 127;
      gload16(w1 + (size_t)(s*128 + row)*128 + col, &Ws[i*2048 + wv*512]);
    }
    __syncthreads();                      // drains As (s=0) + Ws gloads

    // GEMM1: acc1[i][j] = h1^T frags for rows wv*32+i*16+fr, cols j*16+kg*4+r
    f32x4 acc1[2][8];
#pragma unroll
    for (int i = 0; i < 2; ++i)
#pragma unroll
      for (int j = 0; j < 8; ++j) acc1[i][j] = (f32x4)0.f;
#pragma unroll
    for (int ks = 0; ks < 4; ++ks) {
      s16x8 a[2], b[8];
#pragma unroll
      for (int i = 0; i < 2; ++i)
        a[i] = *(const s16x8*)&As[(wv*32 + i*16 + fr)*128 + ks*32 + kg*8];
#pragma unroll
      for (int j = 0; j < 8; ++j)
        b[j] = *(const s16x8*)&Ws[(j*16 + fr)*128 + ks*32 + kg*8];
#pragma unroll
      for (int i = 0; i < 2; ++i)
#pragma unroll
        for (int j = 0; j < 8; ++j)
          acc1[i][j] = __builtin_amdgcn_mfma_f32_16x16x32_bf16(b[j], a[i], acc1[i][j], 0, 0, 0);
    }

    // GEMM2: gelu+cvt in-register, accumulate out-tile
#pragma unroll
    for (int j = 0; j < 8; ++j) {
      f32x4 b1v = *(const f32x4*)&b1[s*128 + j*16 + kg*4];
      s16x4 pa[2];
#pragma unroll
      for (int i = 0; i < 2; ++i) {
        f32x4 v = acc1[i][j];
        pa[i][0] = f2b(fast_gelu(v[0] + b1v.x));
        pa[i][1] = f2b(fast_gelu(v[1] + b1v.y));
        pa[i][2] = f2b(fast_gelu(v[2] + b1v.z));
        pa[i][3] = f2b(fast_gelu(v[3] + b1v.w));
      }
      const int koff = s*128 + j*16 + kg*4;
#pragma unroll
      for (int ct = 0; ct < 8; ++ct) {
        s16x4 wf = *(const s16x4*)&w2[(ct*16 + fr)*512 + koff];
#pragma unroll
        for (int i = 0; i < 2; ++i)
          acc2[i][ct] = mfma16x16x16_bf16(wf, pa[i], acc2[i][ct]);
      }
    }
  }

  // epilogue: out[m][c] = acc2 + b2 + resid (fp16), m = m0+wv*32+i*16+fr,
  // c = ct*16 + kg*4 + r  (vector f32x4 stores)
#pragma unroll
  for (int i = 0; i < 2; ++i) {
    const int m = m0 + wv*32 + i*16 + fr;
#pragma unroll
    for (int ct = 0; ct < 8; ++ct) {
      const int c = ct*16 + kg*4;
      const int base = m*CC + c;
      f32x4 b2v = *(const f32x4*)&b2[c];
      f16x4 rz = *(const f16x4*)&resid[base];
      f32x4 v = acc2[i][ct];
      f32x4 o;
      o.x = v[0] + b2v.x + (float)rz[0];
      o.y = v[1] + b2v.y + (float)rz[1];
      o.z = v[2] + b2v.z + (float)rz[2];
      o.w = v[3] + b2v.w + (float)rz[3];
      *(f32x4*)&out[base] = o;
    }
  }
}

// ---------------------------------------------------------------------------
// Kernel: MFMA window attention (unchanged from R2).
// ---------------------------------------------------------------------------
#define KPAD 20
#define VPAD 264
__global__ __launch_bounds__(256) void attn_mfma_kernel(
    const __hip_bfloat16* __restrict__ qb, const __hip_bfloat16* __restrict__ kb,
    const __hip_bfloat16* __restrict__ vb, __hip_bfloat16* __restrict__ ob) {
  __shared__ __align__(16) short kL[256*KPAD];
  __shared__ __align__(16) short vT[16*VPAD];
  const int bh = blockIdx.x;                // win*8 + head
  const int wid = bh >> 3, head = bh & 7;
  const int tid = threadIdx.x;
  const short* kg = (const short*)kb + (size_t)bh*4096;
  const short* vg = (const short*)vb + (size_t)bh*4096;
  const short* qg = (const short*)qb + (size_t)bh*4096;
  {
    s16x8 a0 = *(const s16x8*)&kg[tid*16];
    s16x8 a1 = *(const s16x8*)&kg[tid*16 + 8];
    *(s16x8*)&kL[tid*KPAD]     = a0;
    *(s16x8*)&kL[tid*KPAD + 8] = a1;
    s16x8 b0 = *(const s16x8*)&vg[tid*16];
    s16x8 b1 = *(const s16x8*)&vg[tid*16 + 8];
#pragma unroll
    for (int d = 0; d < 8; ++d) {
      vT[d*VPAD + tid]     = b0[d];
      vT[(d+8)*VPAD + tid] = b1[d];
    }
  }
  __syncthreads();
  const int wv = tid >> 6, lane = tid & 63;
  const int fr = lane & 15, hi = lane >> 4;
  s16x4 kfrag[16], vfrag[16];
#pragma unroll
  for (int t = 0; t < 16; ++t) {
    kfrag[t] = *(const s16x4*)&kL[(t*16 + fr)*KPAD + hi*4];
    vfrag[t] = *(const s16x4*)&vT[fr*VPAD + t*16 + hi*4];
  }
  short* obs = (short*)ob;
  for (int qt = 0; qt < 4; ++qt) {
    const int q0 = wv*64 + qt*16;
    s16x4 qfrag = *(const s16x4*)&qg[(q0 + fr)*16 + hi*4];
    f32x4 st[16];
#pragma unroll
    for (int kt = 0; kt < 16; ++kt)
      st[kt] = mfma16x16x16_bf16(kfrag[kt], qfrag, (f32x4)0.f);
    float den = 0.f;
    f32x4 oacc = (f32x4)0.f;
#pragma unroll
    for (int kt = 0; kt < 16; ++kt) {
      float e0 = __expf(st[kt][0]), e1 = __expf(st[kt][1]);
      float e2 = __expf(st[kt][2]), e3 = __expf(st[kt][3]);
      den += (e0 + e1) + (e2 + e3);
      s16x4 pa;
      pa[0] = f2b(e0); pa[1] = f2b(e1); pa[2] = f2b(e2); pa[3] = f2b(e3);
      oacc = mfma16x16x16_bf16(vfrag[kt], pa, oacc);
    }
    den += __shfl_xor(den, 16);
    den += __shfl_xor(den, 32);
    float inv = 1.f / den;
    s16x4 ov;
    ov[0] = f2b(oacc[0]*inv); ov[1] = f2b(oacc[1]*inv);
    ov[2] = f2b(oacc[2]*inv); ov[3] = f2b(oacc[3]*inv);
    *(s16x4*)&obs[((size_t)wid*256 + q0 + fr)*CC + head*16 + hi*4] = ov;
  }
}

// ---------------------------------------------------------------------------
// Kernel: FUSED conv3x3x3 (padded bf16 in, NO guards) + exln + norm2.
// R8's proven structure: thread = (site, c8-group), 4 independent t-chains.
// ---------------------------------------------------------------------------
__global__ __launch_bounds__(256) void conv_ln_kernel(
    const __hip_bfloat16* __restrict__ y1p, const float* __restrict__ wT,
    const float* __restrict__ cb,
    const float* __restrict__ exg, const float* __restrict__ exb,
    const float* __restrict__ n2g, const float* __restrict__ n2b,
    _Float16* __restrict__ yb, __hip_bfloat16* __restrict__ h2) {
  const int tid = threadIdx.x;
  const int sp = blockIdx.x*16 + (tid >> 4);     // spatial site 0..16383
  const int cbase = (tid & 15) * 8;              // 8-channel group
  const int w = sp & 31, h = (sp >> 5) & 31, d = sp >> 10;
  const int psite = ((d+1)*PH + (h+1))*PW + (w+1);
  const short* base = (const short*)y1p + (size_t)psite*512 + cbase;

  float acc[4][8];
  {
    f32x4 cb0 = *(const f32x4*)&cb[cbase];
    f32x4 cb1 = *(const f32x4*)&cb[cbase + 4];
#pragma unroll
    for (int t = 0; t < 4; ++t) {
      acc[t][0]=cb0.x; acc[t][1]=cb0.y; acc[t][2]=cb0.z; acc[t][3]=cb0.w;
      acc[t][4]=cb1.x; acc[t][5]=cb1.y; acc[t][6]=cb1.z; acc[t][7]=cb1.w;
    }
  }

#pragma unroll
  for (int dd = -1; dd <= 1; ++dd)
#pragma unroll
    for (int dh = -1; dh <= 1; ++dh)
#pragma unroll
      for (int dw = -1; dw <= 1; ++dw) {
        const int tap = ((dd+1)*3 + (dh+1))*3 + (dw+1);
        const int toff = ((dd*PH + dh)*PW + dw)*512;
        f32x4 w0 = *(const f32x4*)&wT[tap*CC + cbase];
        f32x4 w1 = *(const f32x4*)&wT[tap*CC + cbase + 4];
#pragma unroll
        for (int t = 0; t < 4; ++t) {
          s16x8 v = *(const s16x8*)(base + toff + t*CC);
          acc[t][0] = fmaf(b2f(v[0]), w0.x, acc[t][0]);
          acc[t][1] = fmaf(b2f(v[1]), w0.y, acc[t][1]);
          acc[t][2] = fmaf(b2f(v[2]), w0.z, acc[t][2]);
          acc[t][3] = fmaf(b2f(v[3]), w0.w, acc[t][3]);
          acc[t][4] = fmaf(b2f(v[4]), w1.x, acc[t][4]);
          acc[t][5] = fmaf(b2f(v[5]), w1.y, acc[t][5]);
          acc[t][6] = fmaf(b2f(v[6]), w1.z, acc[t][6]);
          acc[t][7] = fmaf(b2f(v[7]), w1.w, acc[t][7]);
        }
      }

  f32x4 eg0 = *(const f32x4*)&exg[cbase], eg1 = *(const f32x4*)&exg[cbase+4];
  f32x4 eb0 = *(const f32x4*)&exb[cbase], eb1 = *(const f32x4*)&exb[cbase+4];
  f32x4 ng0 = *(const f32x4*)&n2g[cbase], ng1 = *(const f32x4*)&n2g[cbase+4];
  f32x4 nb0 = *(const f32x4*)&n2b[cbase], nb1 = *(const f32x4*)&n2b[cbase+4];
  float eg[8] = {eg0.x,eg0.y,eg0.z,eg0.w,eg1.x,eg1.y,eg1.z,eg1.w};
  float eb[8] = {eb0.x,eb0.y,eb0.z,eb0.w,eb1.x,eb1.y,eb1.z,eb1.w};
  float ng[8] = {ng0.x,ng0.y,ng0.z,ng0.w,ng1.x,ng1.y,ng1.z,ng1.w};
  float nb[8] = {nb0.x,nb0.y,nb0.z,nb0.w,nb1.x,nb1.y,nb1.z,nb1.w};

#pragma unroll
  for (int t = 0; t < 4; ++t) {
    float s = 0.f, sq = 0.f;
#pragma unroll
    for (int c = 0; c < 8; ++c) { s += acc[t][c]; sq = fmaf(acc[t][c], acc[t][c], sq); }
#pragma unroll
    for (int m = 1; m <= 8; m <<= 1) { s += __shfl_xor(s, m); sq += __shfl_xor(sq, m); }
    float mean = s * (1.f/128.f);
    float var  = sq * (1.f/128.f) - mean*mean;
    float rstd = rsqrtf(var + LNEPS);
    float y[8];
    f16x8 yo;
#pragma unroll
    for (int c = 0; c < 8; ++c) {
      y[c] = (acc[t][c] - mean)*rstd*eg[c] + eb[c];
      yo[c] = (_Float16)y[c];
    }
    *(f16x8*)&yb[(size_t)(sp*4 + t)*CC + cbase] = yo;
    float s2 = 0.f, sq2 = 0.f;
#pragma unroll
    for (int c = 0; c < 8; ++c) { s2 += y[c]; sq2 = fmaf(y[c], y[c], sq2); }
#pragma unroll
    for (int m = 1; m <= 8; m <<= 1) { s2 += __shfl_xor(s2, m); sq2 += __shfl_xor(sq2, m); }
    float mean2 = s2 * (1.f/128.f);
    float var2  = sq2 * (1.f/128.f) - mean2*mean2;
    float rstd2 = rsqrtf(var2 + LNEPS);
    s16x8 ho;
#pragma unroll
    for (int c = 0; c < 8; ++c)
      ho[c] = f2b((y[c] - mean2)*rstd2*ng[c] + nb[c]);
    *(s16x8*)&((short*)h2)[(size_t)(sp*4 + t)*CC + cbase] = ho;
  }
}

// ---------------------------------------------------------------------------
// Launch
// ---------------------------------------------------------------------------
extern "C" void kernel_launch(void* const* d_in, const int* in_sizes, int n_in,
                              void* d_out, int out_size, void* d_ws, size_t ws_size,
                              hipStream_t stream) {
  const float* x      = (const float*)d_in[0];
  const float* n1g    = (const float*)d_in[1];
  const float* n1b    = (const float*)d_in[2];
  const float* pos    = (const float*)d_in[3];
  const float* te     = (const float*)d_in[4];
  const float* qkv_w  = (const float*)d_in[5];
  const float* qkv_b  = (const float*)d_in[6];
  const float* proj_w = (const float*)d_in[7];
  const float* proj_b = (const float*)d_in[8];
  const float* conv_w = (const float*)d_in[9];
  const float* conv_b = (const float*)d_in[10];
  const float* exg    = (const float*)d_in[11];
  const float* exb    = (const float*)d_in[12];
  const float* n2g    = (const float*)d_in[13];
  const float* n2b    = (const float*)d_in[14];
  const float* fc1_w  = (const float*)d_in[15];
  const float* fc1_b  = (const float*)d_in[16];
  const float* fc2_w  = (const float*)d_in[17];
  const float* fc2_b  = (const float*)d_in[18];

  char* wsb = (char*)d_ws;
  __hip_bfloat16* wq  = (__hip_bfloat16*)(wsb);             // 384x128
  __hip_bfloat16* wp  = (__hip_bfloat16*)(wsb + 98304);     // 128x128
  __hip_bfloat16* w1  = (__hip_bfloat16*)(wsb + 131072);    // 512x128
  __hip_bfloat16* w2  = (__hip_bfloat16*)(wsb + 262144);    // 128x512
  float*          cwT = (float*)(wsb + 393216);             // 27x128

  const size_t A_OFF = (size_t)1 << 20;                     // 16 MiB region
  const size_t B_OFF = A_OFF + ((size_t)16 << 20);          // 48 MiB region

  __hip_bfloat16* hbuf = (__hip_bfloat16*)(wsb + A_OFF);    // LN1 out
  __hip_bfloat16* obuf = (__hip_bfloat16*)(wsb + A_OFF);    // attn out (reuses A)
  __hip_bfloat16* h2in = (__hip_bfloat16*)(wsb + A_OFF);    // MLP in (reuses A)
  __hip_bfloat16* qkvb = (__hip_bfloat16*)(wsb + B_OFF);    // q|k|v, 16MiB each
  __hip_bfloat16* qb   = qkvb;
  __hip_bfloat16* kb   = qkvb + 8388608;
  __hip_bfloat16* vb   = qkvb + 16777216;
  __hip_bfloat16* y1p  = (__hip_bfloat16*)(wsb + B_OFF);    // padded proj out (20.3 MiB, over q+k)
  _Float16* yb = (_Float16*)(wsb + B_OFF + ((size_t)24 << 20)); // fp16 y (16 MiB)

  prep_kernel<<<782, 256, 0, stream>>>(qkv_w, proj_w, fc1_w, fc2_w, conv_w,
                                       wq, wp, w1, w2, cwT);
  ln1_pe_kernel<<<TOKS/4, 256, 0, stream>>>(x, n1g, n1b, pos, te, hbuf);
  gemm_kernel<0, 128><<<dim3(TOKS/128, 3), 256, 0, stream>>>(
      (const short*)hbuf, (const short*)wq, qkv_b, (void*)qkvb, nullptr);
  attn_mfma_kernel<<<NWIN*8, 256, 0, stream>>>(qb, kb, vb, obuf);
  border_zero_kernel<<<(PSITES*64 + 255)/256, 256, 0, stream>>>((short*)y1p);
  gemm_kernel<1, 128><<<dim3(TOKS/128, 1), 256, 0, stream>>>(
      (const short*)obuf, (const short*)wp, proj_b, (void*)y1p, nullptr);
  conv_ln_kernel<<<16384/16, 256, 0, stream>>>(y1p, cwT, conv_b,
      exg, exb, n2g, n2b, yb, h2in);
  mlp_kernel<<<TOKS/128, 256, 0, stream>>>(
      (const short*)h2in, (const short*)w1, (const short*)w2,
      fc1_b, fc2_b, yb, (float*)d_out);
}

// Round 16
// 212.535 us; speedup vs baseline: 1.0739x; 1.0739x over previous
//
#include <hip/hip_runtime.h>
#include <hip/hip_bf16.h>

// ---------------------------------------------------------------------------
// CrossFormerBlock on MI355X (gfx950)
// B=1 D=16 H=32 W=32 T=4 C=128, G=4, NH=8, HD=16, NW=256 windows, N=256 tok/win
// R16: fused MLP v2 — fixes R15's three failures: (1) w2 prepacked into
// fragment order (w2f) -> GEMM2 loads fully coalesced (was 16-way scatter);
// (2) LDS 48KB (As 2x[128][64] + Ws [128][64]) -> 3 blocks/CU (was 2);
// (3) GEMM1 in R13's exact BK=64 MFMA order -> bit-identical h1.
// qkv/proj GEMMs, attention, conv, border_zero: exact R13 configuration.
// ---------------------------------------------------------------------------

typedef __attribute__((ext_vector_type(8))) short  s16x8;
typedef __attribute__((ext_vector_type(4))) short  s16x4;
typedef __attribute__((ext_vector_type(4))) float  f32x4;
typedef __attribute__((ext_vector_type(8))) _Float16 f16x8;
typedef __attribute__((ext_vector_type(4))) _Float16 f16x4;

#define CC    128
#define NWIN  256
#define TOKS  65536            // total tokens = D*H*W*T
#define SCALE 0.25f
#define LNEPS 1e-5f
// padded spatial geometry for conv
#define PD 18
#define PH 34
#define PW 34
#define PSITES (PD*PH*PW)                // 20808
#define Y1P_SHORTS ((size_t)PSITES*512)  // *4t*128c

__device__ __forceinline__ float b2f(short s) {
  union { unsigned u; float f; } c; c.u = ((unsigned)(unsigned short)s) << 16; return c.f;
}
__device__ __forceinline__ short f2b(float f) {
  __hip_bfloat16 h = __float2bfloat16(f);
  return *reinterpret_cast<short*>(&h);
}
__device__ __forceinline__ float fast_gelu(float x) {
  float u = 1.595769122f * x * fmaf(0.044715f, x*x, 1.0f);
  return x / (1.0f + __expf(-u));
}

__device__ __forceinline__ f32x4 mfma16x16x16_bf16(s16x4 a, s16x4 b, f32x4 c) {
#if __has_builtin(__builtin_amdgcn_mfma_f32_16x16x16_bf16)
  return __builtin_amdgcn_mfma_f32_16x16x16_bf16(a, b, c, 0, 0, 0);
#elif __has_builtin(__builtin_amdgcn_mfma_f32_16x16x16bf16_1k)
  return __builtin_amdgcn_mfma_f32_16x16x16bf16_1k(a, b, c, 0, 0, 0);
#else
  f32x4 d;
  asm("v_mfma_f32_16x16x16_bf16 %0, %1, %2, %3" : "=v"(d) : "v"(a), "v"(b), "v"(c));
  return d;
#endif
}

// async global->LDS, 16B per lane; lds base wave-uniform (HW appends lane*16).
__device__ __forceinline__ void gload16(const short* g, short* l) {
  __builtin_amdgcn_global_load_lds(
      (const __attribute__((address_space(1))) void*)g,
      (__attribute__((address_space(3))) void*)l, 16, 0, 0);
}

// ---------------------------------------------------------------------------
// Kernel 0: weight prep (+ w2f fragment prepack for the fused MLP)
// w2f layout: frag f=(s*8+j)*8+ct, element (lane, r):
//   w2f[f*256 + lane*4 + r] = fc2_w[(ct*16 + (lane&15))*512 + s*128 + j*16 + (lane>>4)*4 + r]
// ---------------------------------------------------------------------------
__global__ void prep_kernel(const float* __restrict__ qkv_w, const float* __restrict__ proj_w,
                            const float* __restrict__ fc1_w, const float* __restrict__ fc2_w,
                            const float* __restrict__ conv_w,
                            __hip_bfloat16* wq, __hip_bfloat16* wp,
                            __hip_bfloat16* w1, __hip_bfloat16* w2f, float* cwT) {
  int idx = blockIdx.x * 256 + threadIdx.x;
  if (idx < 49152) {
    wq[idx] = __float2bfloat16(qkv_w[idx]);
  } else if (idx < 65536) {
    wp[idx - 49152] = __float2bfloat16(proj_w[idx - 49152]);
  } else if (idx < 131072) {
    w1[idx - 65536] = __float2bfloat16(fc1_w[idx - 65536]);
  } else if (idx < 131072 + 27*128) {
    int j = idx - 131072;
    int tap = j >> 7, c = j & 127;
    cwT[tap*128 + c] = conv_w[c*27 + tap];   // (C,1,3,3,3) -> (27,C)
  } else if (idx < 131072 + 3456 + 65536) {
    int j2 = idx - (131072 + 3456);
    int r = j2 & 3, lane = (j2 >> 2) & 63, f = j2 >> 8;
    int fr = lane & 15, kg = lane >> 4;
    int s = f >> 6, jj = (f >> 3) & 7, ct = f & 7;
    w2f[j2] = __float2bfloat16(fc2_w[(ct*16 + fr)*512 + s*128 + jj*16 + kg*4 + r]);
  }
}

// ---------------------------------------------------------------------------
// Kernel: zero only the BORDER sites of the padded y1 buffer (4424 sites).
// ---------------------------------------------------------------------------
__global__ __launch_bounds__(256) void border_zero_kernel(short* __restrict__ y1p) {
  int idx = blockIdx.x*256 + threadIdx.x;
  if (idx >= PSITES*64) return;
  int site = idx >> 6;
  int w = site % PW, hh = (site / PW) % PH, d = site / (PW*PH);
  if (d != 0 && d != PD-1 && hh != 0 && hh != PH-1 && w != 0 && w != PW-1) return;
  *(s16x8*)&y1p[(size_t)site*512 + (idx & 63)*8] = (s16x8)0;
}

// ---------------------------------------------------------------------------
// Kernel 1: LN1 + positional/temporal embed -> window-token layout bf16
// ---------------------------------------------------------------------------
__global__ __launch_bounds__(256) void ln1_pe_kernel(
    const float* __restrict__ x, const float* __restrict__ g, const float* __restrict__ b,
    const float* __restrict__ pos, const float* __restrict__ te,
    __hip_bfloat16* __restrict__ hb) {
  int wv = threadIdx.x >> 6, lane = threadIdx.x & 63;
  int tk = blockIdx.x * 4 + wv;                 // tk = wid*256 + n
  int wid = tk >> 8, n = tk & 255;
  int t = n >> 6, gd = (n >> 4) & 3, gh = (n >> 2) & 3, gw = n & 3;
  int wd = wid >> 6, wh = (wid >> 3) & 7, ww = wid & 7;
  int d = wd*4 + gd, h = wh*4 + gh, w = ww*4 + gw;
  size_t xoff = ((size_t)((d*32 + h)*32 + w)*4 + t) * CC;
  float v0 = x[xoff + lane], v1 = x[xoff + lane + 64];
  float s = v0 + v1, sq = v0*v0 + v1*v1;
  for (int m = 32; m; m >>= 1) { s += __shfl_xor(s, m); sq += __shfl_xor(sq, m); }
  float mean = s * (1.f/128.f);
  float var  = sq * (1.f/128.f) - mean*mean;
  float rstd = rsqrtf(var + LNEPS);
  int pb = ((gd*4 + gh)*4 + gw) * CC, tb = t * CC;
  float h0 = (v0 - mean)*rstd*g[lane]    + b[lane]    + pos[pb + lane]    + te[tb + lane];
  float h1 = (v1 - mean)*rstd*g[lane+64] + b[lane+64] + pos[pb + lane+64] + te[tb + lane+64];
  hb[(size_t)tk*CC + lane]      = __float2bfloat16(h0);
  hb[(size_t)tk*CC + lane + 64] = __float2bfloat16(h1);
}

// ---------------------------------------------------------------------------
// GEMM template (R13): 128x128 tile, BK=64, 4 waves, compile-time K.
// Staging: global_load_lds width=16, LINEAR LDS [128][64].
// MODE 0: qkv split; MODE 1: proj -> PADDED spatial scatter bf16.
// ---------------------------------------------------------------------------
template <int MODE, int KK>
__global__ __launch_bounds__(256) void gemm_kernel(
    const short* __restrict__ Ag, const short* __restrict__ Wg,
    const float* __restrict__ bias, void* __restrict__ out0) {
  __shared__ __align__(16) short As[128*64];
  __shared__ __align__(16) short Bs[128*64];
  const int tid = threadIdx.x;
  const int m0 = blockIdx.x * 128;
  const int n0 = blockIdx.y * 128;
  const int lane = tid & 63, wv = tid >> 6;
  const int wr = wv >> 1, wc = wv & 1;
  const int fr = lane & 15, kg = lane >> 4;

  f32x4 acc[4][4];
#pragma unroll
  for (int i = 0; i < 4; ++i)
#pragma unroll
    for (int j = 0; j < 4; ++j) acc[i][j] = (f32x4)0.f;

#pragma unroll
  for (int kc = 0; kc < KK; kc += 64) {
    __syncthreads();
#pragma unroll
    for (int i = 0; i < 4; ++i) {
      const int e = i*2048 + tid*8;          // short index in 128x64 tile
      const int row = e >> 6, col = e & 63;
      gload16(Ag + (size_t)(m0 + row)*KK + kc + col, &As[i*2048 + wv*512]);
      gload16(Wg + (size_t)(n0 + row)*KK + kc + col, &Bs[i*2048 + wv*512]);
    }
    __syncthreads();
#pragma unroll
    for (int ks = 0; ks < 2; ++ks) {
      s16x8 a[4], b[4];
#pragma unroll
      for (int i = 0; i < 4; ++i)
        a[i] = *(const s16x8*)&As[(wr*64 + i*16 + fr)*64 + ks*32 + kg*8];
#pragma unroll
      for (int j = 0; j < 4; ++j)
        b[j] = *(const s16x8*)&Bs[(wc*64 + j*16 + fr)*64 + ks*32 + kg*8];
#pragma unroll
      for (int i = 0; i < 4; ++i)
#pragma unroll
        for (int j = 0; j < 4; ++j)
          acc[i][j] = __builtin_amdgcn_mfma_f32_16x16x32_bf16(b[j], a[i], acc[i][j], 0, 0, 0);
    }
  }

  const int nbb = n0 + wc*64 + kg*4;
  f32x4 bj4[4];
#pragma unroll
  for (int j = 0; j < 4; ++j) bj4[j] = *(const f32x4*)&bias[nbb + j*16];

#pragma unroll
  for (int i = 0; i < 4; ++i) {
    const int m = m0 + wr*64 + i*16 + fr;
    if constexpr (MODE == 0) {
      short* qs = (short*)out0;
      const int sec = n0 >> 7;
      const float scl = (sec == 0) ? SCALE : 1.0f;
      const int wid = m >> 8, ntok = m & 255;
      const int rowbase = sec*8388608 + (wid*8)*4096 + ntok*16 + (nbb & 15);
#pragma unroll
      for (int j = 0; j < 4; ++j) {
        const int head = ((nbb + j*16) >> 4) & 7;
        f32x4 v = acc[i][j];
        s16x4 o;
        o[0] = f2b(fmaf(v[0], scl, bj4[j].x*scl));
        o[1] = f2b(fmaf(v[1], scl, bj4[j].y*scl));
        o[2] = f2b(fmaf(v[2], scl, bj4[j].z*scl));
        o[3] = f2b(fmaf(v[3], scl, bj4[j].w*scl));
        *(s16x4*)&qs[rowbase + head*4096] = o;
      }
    } else {
      short* y1o = (short*)out0;       // PADDED [18][34][34][4][128]
      const int wid = m >> 8, ntok = m & 255;
      const int t = ntok >> 6, gd = (ntok >> 4) & 3, gh = (ntok >> 2) & 3, gw = ntok & 3;
      const int wd = wid >> 6, wh = (wid >> 3) & 7, ww = wid & 7;
      const int sr = (((wd*4 + gd + 1)*PH + wh*4 + gh + 1)*PW + ww*4 + gw + 1)*4 + t;
      const int base = sr*CC + nbb;
#pragma unroll
      for (int j = 0; j < 4; ++j) {
        f32x4 v = acc[i][j];
        s16x4 o;
        o[0] = f2b(v[0] + bj4[j].x); o[1] = f2b(v[1] + bj4[j].y);
        o[2] = f2b(v[2] + bj4[j].z); o[3] = f2b(v[3] + bj4[j].w);
        *(s16x4*)&y1o[base + j*16] = o;
      }
    }
  }
}

// ---------------------------------------------------------------------------
// Kernel: FUSED MLP v2 — out = gelu(h2 @ w1^T + b1) @ w2^T + b2 + resid.
// 512 blocks x 4 waves; wave owns 32 rows. LDS 48KB (3 blocks/CU):
// As = 2x[128][64] (h2, staged once), Ws = [128][64] (w1 slice, re-staged
// per (s,half)). GEMM1 = R13's exact BK=64 MFMA order -> identical h1.
// GEMM2: gelu+cvt in-register; w2 fragments read COALESCED from prepacked
// w2f (L2-resident). h1 never touches memory.
// ---------------------------------------------------------------------------
__global__ __launch_bounds__(256) void mlp_kernel(
    const short* __restrict__ h2, const short* __restrict__ w1,
    const short* __restrict__ w2f, const float* __restrict__ b1,
    const float* __restrict__ b2, const _Float16* __restrict__ resid,
    float* __restrict__ out) {
  __shared__ __align__(16) short As[2][128*64];
  __shared__ __align__(16) short Ws[128*64];
  const int tid = threadIdx.x;
  const int m0 = blockIdx.x * 128;
  const int lane = tid & 63, wv = tid >> 6;
  const int fr = lane & 15, kg = lane >> 4;

  // stage h2 tile (both K-halves) once
#pragma unroll
  for (int half = 0; half < 2; ++half)
#pragma unroll
    for (int i = 0; i < 4; ++i) {
      const int e = i*2048 + tid*8;
      const int row = e >> 6, col = e & 63;
      gload16(h2 + (size_t)(m0 + row)*128 + half*64 + col, &As[half][i*2048 + wv*512]);
    }

  f32x4 acc2[2][8];
#pragma unroll
  for (int i = 0; i < 2; ++i)
#pragma unroll
    for (int c = 0; c < 8; ++c) acc2[i][c] = (f32x4)0.f;

#pragma unroll
  for (int s = 0; s < 4; ++s) {
    f32x4 acc1[2][8];
#pragma unroll
    for (int i = 0; i < 2; ++i)
#pragma unroll
      for (int j = 0; j < 8; ++j) acc1[i][j] = (f32x4)0.f;

#pragma unroll
    for (int half = 0; half < 2; ++half) {
      __syncthreads();                    // Ws readers of prev round done
#pragma unroll
      for (int i = 0; i < 4; ++i) {
        const int e = i*2048 + tid*8;
        const int row = e >> 6, col = e & 63;
        gload16(w1 + (size_t)(s*128 + row)*128 + half*64 + col, &Ws[i*2048 + wv*512]);
      }
      __syncthreads();                    // drains Ws (+As on first pass)
#pragma unroll
      for (int ks = 0; ks < 2; ++ks) {
        s16x8 a[2], b[8];
#pragma unroll
        for (int i = 0; i < 2; ++i)
          a[i] = *(const s16x8*)&As[half][(wv*32 + i*16 + fr)*64 + ks*32 + kg*8];
#pragma unroll
        for (int j = 0; j < 8; ++j)
          b[j] = *(const s16x8*)&Ws[(j*16 + fr)*64 + ks*32 + kg*8];
#pragma unroll
        for (int i = 0; i < 2; ++i)
#pragma unroll
          for (int j = 0; j < 8; ++j)
            acc1[i][j] = __builtin_amdgcn_mfma_f32_16x16x32_bf16(b[j], a[i], acc1[i][j], 0, 0, 0);
      }
    }

    // GEMM2: gelu+cvt in-register; D^T frag (lane holds h1[m=fr][k=kg*4+r])
    // IS the 16x16x16 A-operand. w2f fragment loads are coalesced 512B.
#pragma unroll
    for (int j = 0; j < 8; ++j) {
      f32x4 b1v = *(const f32x4*)&b1[s*128 + j*16 + kg*4];
      s16x4 pa[2];
#pragma unroll
      for (int i = 0; i < 2; ++i) {
        f32x4 v = acc1[i][j];
        pa[i][0] = f2b(fast_gelu(v[0] + b1v.x));
        pa[i][1] = f2b(fast_gelu(v[1] + b1v.y));
        pa[i][2] = f2b(fast_gelu(v[2] + b1v.z));
        pa[i][3] = f2b(fast_gelu(v[3] + b1v.w));
      }
      const int fb = ((s*8 + j)*8)*256 + lane*4;
#pragma unroll
      for (int ct = 0; ct < 8; ++ct) {
        s16x4 wf = *(const s16x4*)&w2f[fb + ct*256];
#pragma unroll
        for (int i = 0; i < 2; ++i)
          acc2[i][ct] = mfma16x16x16_bf16(wf, pa[i], acc2[i][ct]);
      }
    }
  }

  // epilogue: out[m][c] = acc2 + b2 + resid (fp16), c = ct*16 + kg*4 + r
#pragma unroll
  for (int i = 0; i < 2; ++i) {
    const int m = m0 + wv*32 + i*16 + fr;
#pragma unroll
    for (int ct = 0; ct < 8; ++ct) {
      const int c = ct*16 + kg*4;
      const int base = m*CC + c;
      f32x4 b2v = *(const f32x4*)&b2[c];
      f16x4 rz = *(const f16x4*)&resid[base];
      f32x4 v = acc2[i][ct];
      f32x4 o;
      o.x = v[0] + b2v.x + (float)rz[0];
      o.y = v[1] + b2v.y + (float)rz[1];
      o.z = v[2] + b2v.z + (float)rz[2];
      o.w = v[3] + b2v.w + (float)rz[3];
      *(f32x4*)&out[base] = o;
    }
  }
}

// ---------------------------------------------------------------------------
// Kernel: MFMA window attention (unchanged from R2).
// ---------------------------------------------------------------------------
#define KPAD 20
#define VPAD 264
__global__ __launch_bounds__(256) void attn_mfma_kernel(
    const __hip_bfloat16* __restrict__ qb, const __hip_bfloat16* __restrict__ kb,
    const __hip_bfloat16* __restrict__ vb, __hip_bfloat16* __restrict__ ob) {
  __shared__ __align__(16) short kL[256*KPAD];
  __shared__ __align__(16) short vT[16*VPAD];
  const int bh = blockIdx.x;                // win*8 + head
  const int wid = bh >> 3, head = bh & 7;
  const int tid = threadIdx.x;
  const short* kg = (const short*)kb + (size_t)bh*4096;
  const short* vg = (const short*)vb + (size_t)bh*4096;
  const short* qg = (const short*)qb + (size_t)bh*4096;
  {
    s16x8 a0 = *(const s16x8*)&kg[tid*16];
    s16x8 a1 = *(const s16x8*)&kg[tid*16 + 8];
    *(s16x8*)&kL[tid*KPAD]     = a0;
    *(s16x8*)&kL[tid*KPAD + 8] = a1;
    s16x8 b0 = *(const s16x8*)&vg[tid*16];
    s16x8 b1 = *(const s16x8*)&vg[tid*16 + 8];
#pragma unroll
    for (int d = 0; d < 8; ++d) {
      vT[d*VPAD + tid]     = b0[d];
      vT[(d+8)*VPAD + tid] = b1[d];
    }
  }
  __syncthreads();
  const int wv = tid >> 6, lane = tid & 63;
  const int fr = lane & 15, hi = lane >> 4;
  s16x4 kfrag[16], vfrag[16];
#pragma unroll
  for (int t = 0; t < 16; ++t) {
    kfrag[t] = *(const s16x4*)&kL[(t*16 + fr)*KPAD + hi*4];
    vfrag[t] = *(const s16x4*)&vT[fr*VPAD + t*16 + hi*4];
  }
  short* obs = (short*)ob;
  for (int qt = 0; qt < 4; ++qt) {
    const int q0 = wv*64 + qt*16;
    s16x4 qfrag = *(const s16x4*)&qg[(q0 + fr)*16 + hi*4];
    f32x4 st[16];
#pragma unroll
    for (int kt = 0; kt < 16; ++kt)
      st[kt] = mfma16x16x16_bf16(kfrag[kt], qfrag, (f32x4)0.f);
    float den = 0.f;
    f32x4 oacc = (f32x4)0.f;
#pragma unroll
    for (int kt = 0; kt < 16; ++kt) {
      float e0 = __expf(st[kt][0]), e1 = __expf(st[kt][1]);
      float e2 = __expf(st[kt][2]), e3 = __expf(st[kt][3]);
      den += (e0 + e1) + (e2 + e3);
      s16x4 pa;
      pa[0] = f2b(e0); pa[1] = f2b(e1); pa[2] = f2b(e2); pa[3] = f2b(e3);
      oacc = mfma16x16x16_bf16(vfrag[kt], pa, oacc);
    }
    den += __shfl_xor(den, 16);
    den += __shfl_xor(den, 32);
    float inv = 1.f / den;
    s16x4 ov;
    ov[0] = f2b(oacc[0]*inv); ov[1] = f2b(oacc[1]*inv);
    ov[2] = f2b(oacc[2]*inv); ov[3] = f2b(oacc[3]*inv);
    *(s16x4*)&obs[((size_t)wid*256 + q0 + fr)*CC + head*16 + hi*4] = ov;
  }
}

// ---------------------------------------------------------------------------
// Kernel: FUSED conv3x3x3 (padded bf16 in, NO guards) + exln + norm2.
// R8's proven structure: thread = (site, c8-group), 4 independent t-chains.
// ---------------------------------------------------------------------------
__global__ __launch_bounds__(256) void conv_ln_kernel(
    const __hip_bfloat16* __restrict__ y1p, const float* __restrict__ wT,
    const float* __restrict__ cb,
    const float* __restrict__ exg, const float* __restrict__ exb,
    const float* __restrict__ n2g, const float* __restrict__ n2b,
    _Float16* __restrict__ yb, __hip_bfloat16* __restrict__ h2) {
  const int tid = threadIdx.x;
  const int sp = blockIdx.x*16 + (tid >> 4);     // spatial site 0..16383
  const int cbase = (tid & 15) * 8;              // 8-channel group
  const int w = sp & 31, h = (sp >> 5) & 31, d = sp >> 10;
  const int psite = ((d+1)*PH + (h+1))*PW + (w+1);
  const short* base = (const short*)y1p + (size_t)psite*512 + cbase;

  float acc[4][8];
  {
    f32x4 cb0 = *(const f32x4*)&cb[cbase];
    f32x4 cb1 = *(const f32x4*)&cb[cbase + 4];
#pragma unroll
    for (int t = 0; t < 4; ++t) {
      acc[t][0]=cb0.x; acc[t][1]=cb0.y; acc[t][2]=cb0.z; acc[t][3]=cb0.w;
      acc[t][4]=cb1.x; acc[t][5]=cb1.y; acc[t][6]=cb1.z; acc[t][7]=cb1.w;
    }
  }

#pragma unroll
  for (int dd = -1; dd <= 1; ++dd)
#pragma unroll
    for (int dh = -1; dh <= 1; ++dh)
#pragma unroll
      for (int dw = -1; dw <= 1; ++dw) {
        const int tap = ((dd+1)*3 + (dh+1))*3 + (dw+1);
        const int toff = ((dd*PH + dh)*PW + dw)*512;
        f32x4 w0 = *(const f32x4*)&wT[tap*CC + cbase];
        f32x4 w1 = *(const f32x4*)&wT[tap*CC + cbase + 4];
#pragma unroll
        for (int t = 0; t < 4; ++t) {
          s16x8 v = *(const s16x8*)(base + toff + t*CC);
          acc[t][0] = fmaf(b2f(v[0]), w0.x, acc[t][0]);
          acc[t][1] = fmaf(b2f(v[1]), w0.y, acc[t][1]);
          acc[t][2] = fmaf(b2f(v[2]), w0.z, acc[t][2]);
          acc[t][3] = fmaf(b2f(v[3]), w0.w, acc[t][3]);
          acc[t][4] = fmaf(b2f(v[4]), w1.x, acc[t][4]);
          acc[t][5] = fmaf(b2f(v[5]), w1.y, acc[t][5]);
          acc[t][6] = fmaf(b2f(v[6]), w1.z, acc[t][6]);
          acc[t][7] = fmaf(b2f(v[7]), w1.w, acc[t][7]);
        }
      }

  f32x4 eg0 = *(const f32x4*)&exg[cbase], eg1 = *(const f32x4*)&exg[cbase+4];
  f32x4 eb0 = *(const f32x4*)&exb[cbase], eb1 = *(const f32x4*)&exb[cbase+4];
  f32x4 ng0 = *(const f32x4*)&n2g[cbase], ng1 = *(const f32x4*)&n2g[cbase+4];
  f32x4 nb0 = *(const f32x4*)&n2b[cbase], nb1 = *(const f32x4*)&n2b[cbase+4];
  float eg[8] = {eg0.x,eg0.y,eg0.z,eg0.w,eg1.x,eg1.y,eg1.z,eg1.w};
  float eb[8] = {eb0.x,eb0.y,eb0.z,eb0.w,eb1.x,eb1.y,eb1.z,eb1.w};
  float ng[8] = {ng0.x,ng0.y,ng0.z,ng0.w,ng1.x,ng1.y,ng1.z,ng1.w};
  float nb[8] = {nb0.x,nb0.y,nb0.z,nb0.w,nb1.x,nb1.y,nb1.z,nb1.w};

#pragma unroll
  for (int t = 0; t < 4; ++t) {
    float s = 0.f, sq = 0.f;
#pragma unroll
    for (int c = 0; c < 8; ++c) { s += acc[t][c]; sq = fmaf(acc[t][c], acc[t][c], sq); }
#pragma unroll
    for (int m = 1; m <= 8; m <<= 1) { s += __shfl_xor(s, m); sq += __shfl_xor(sq, m); }
    float mean = s * (1.f/128.f);
    float var  = sq * (1.f/128.f) - mean*mean;
    float rstd = rsqrtf(var + LNEPS);
    float y[8];
    f16x8 yo;
#pragma unroll
    for (int c = 0; c < 8; ++c) {
      y[c] = (acc[t][c] - mean)*rstd*eg[c] + eb[c];
      yo[c] = (_Float16)y[c];
    }
    *(f16x8*)&yb[(size_t)(sp*4 + t)*CC + cbase] = yo;
    float s2 = 0.f, sq2 = 0.f;
#pragma unroll
    for (int c = 0; c < 8; ++c) { s2 += y[c]; sq2 = fmaf(y[c], y[c], sq2); }
#pragma unroll
    for (int m = 1; m <= 8; m <<= 1) { s2 += __shfl_xor(s2, m); sq2 += __shfl_xor(sq2, m); }
    float mean2 = s2 * (1.f/128.f);
    float var2  = sq2 * (1.f/128.f) - mean2*mean2;
    float rstd2 = rsqrtf(var2 + LNEPS);
    s16x8 ho;
#pragma unroll
    for (int c = 0; c < 8; ++c)
      ho[c] = f2b((y[c] - mean2)*rstd2*ng[c] + nb[c]);
    *(s16x8*)&((short*)h2)[(size_t)(sp*4 + t)*CC + cbase] = ho;
  }
}

// ---------------------------------------------------------------------------
// Launch
// ---------------------------------------------------------------------------
extern "C" void kernel_launch(void* const* d_in, const int* in_sizes, int n_in,
                              void* d_out, int out_size, void* d_ws, size_t ws_size,
                              hipStream_t stream) {
  const float* x      = (const float*)d_in[0];
  const float* n1g    = (const float*)d_in[1];
  const float* n1b    = (const float*)d_in[2];
  const float* pos    = (const float*)d_in[3];
  const float* te     = (const float*)d_in[4];
  const float* qkv_w  = (const float*)d_in[5];
  const float* qkv_b  = (const float*)d_in[6];
  const float* proj_w = (const float*)d_in[7];
  const float* proj_b = (const float*)d_in[8];
  const float* conv_w = (const float*)d_in[9];
  const float* conv_b = (const float*)d_in[10];
  const float* exg    = (const float*)d_in[11];
  const float* exb    = (const float*)d_in[12];
  const float* n2g    = (const float*)d_in[13];
  const float* n2b    = (const float*)d_in[14];
  const float* fc1_w  = (const float*)d_in[15];
  const float* fc1_b  = (const float*)d_in[16];
  const float* fc2_w  = (const float*)d_in[17];
  const float* fc2_b  = (const float*)d_in[18];

  char* wsb = (char*)d_ws;
  __hip_bfloat16* wq  = (__hip_bfloat16*)(wsb);             // 384x128
  __hip_bfloat16* wp  = (__hip_bfloat16*)(wsb + 98304);     // 128x128
  __hip_bfloat16* w1  = (__hip_bfloat16*)(wsb + 131072);    // 512x128
  float*          cwT = (float*)(wsb + 262144);             // 27x128 (13824B)
  __hip_bfloat16* w2f = (__hip_bfloat16*)(wsb + 276480);    // 256 frags x 256 (128KB)

  const size_t A_OFF = (size_t)1 << 20;                     // 16 MiB region
  const size_t B_OFF = A_OFF + ((size_t)16 << 20);          // 48 MiB region

  __hip_bfloat16* hbuf = (__hip_bfloat16*)(wsb + A_OFF);    // LN1 out
  __hip_bfloat16* obuf = (__hip_bfloat16*)(wsb + A_OFF);    // attn out (reuses A)
  __hip_bfloat16* h2in = (__hip_bfloat16*)(wsb + A_OFF);    // MLP in (reuses A)
  __hip_bfloat16* qkvb = (__hip_bfloat16*)(wsb + B_OFF);    // q|k|v, 16MiB each
  __hip_bfloat16* qb   = qkvb;
  __hip_bfloat16* kb   = qkvb + 8388608;
  __hip_bfloat16* vb   = qkvb + 16777216;
  __hip_bfloat16* y1p  = (__hip_bfloat16*)(wsb + B_OFF);    // padded proj out (20.3 MiB)
  _Float16* yb = (_Float16*)(wsb + B_OFF + ((size_t)24 << 20)); // fp16 y (16 MiB)

  // prep covers 131072+3456+65536 = 200064 elements -> 782 blocks
  prep_kernel<<<782, 256, 0, stream>>>(qkv_w, proj_w, fc1_w, fc2_w, conv_w,
                                       wq, wp, w1, w2f, cwT);
  ln1_pe_kernel<<<TOKS/4, 256, 0, stream>>>(x, n1g, n1b, pos, te, hbuf);
  gemm_kernel<0, 128><<<dim3(TOKS/128, 3), 256, 0, stream>>>(
      (const short*)hbuf, (const short*)wq, qkv_b, (void*)qkvb);
  attn_mfma_kernel<<<NWIN*8, 256, 0, stream>>>(qb, kb, vb, obuf);
  border_zero_kernel<<<(PSITES*64 + 255)/256, 256, 0, stream>>>((short*)y1p);
  gemm_kernel<1, 128><<<dim3(TOKS/128, 1), 256, 0, stream>>>(
      (const short*)obuf, (const short*)wp, proj_b, (void*)y1p);
  conv_ln_kernel<<<16384/16, 256, 0, stream>>>(y1p, cwT, conv_b,
      exg, exb, n2g, n2b, yb, h2in);
  mlp_kernel<<<TOKS/128, 256, 0, stream>>>(
      (const short*)h2in, (const short*)w1, (const short*)w2f,
      fc1_b, fc2_b, yb, (float*)d_out);
}

// Round 17
// 189.173 us; speedup vs baseline: 1.2065x; 1.1235x over previous
//
#include <hip/hip_runtime.h>
#include <hip/hip_bf16.h>

// ---------------------------------------------------------------------------
// CrossFormerBlock on MI355X (gfx950)
// B=1 D=16 H=32 W=32 T=4 C=128, G=4, NH=8, HD=16, NW=256 windows, N=256 tok/win
// R17: fused MLP v3 — occupancy fix: BM=64 (grid 1024, 4 blocks/CU of work),
// LDS 32KB (As 2x[64][64] + Ws [128][64]) -> ~3 blocks/CU resident vs R16's
// ~1. R16 counters showed latency-bound (HBM 7%, VALU 22%, MFMA 10%, occ 10%)
// with only 512 serial blocks. Same math order -> bit-identical output.
// Everything else identical to R16 (= R13 config).
// ---------------------------------------------------------------------------

typedef __attribute__((ext_vector_type(8))) short  s16x8;
typedef __attribute__((ext_vector_type(4))) short  s16x4;
typedef __attribute__((ext_vector_type(4))) float  f32x4;
typedef __attribute__((ext_vector_type(8))) _Float16 f16x8;
typedef __attribute__((ext_vector_type(4))) _Float16 f16x4;

#define CC    128
#define NWIN  256
#define TOKS  65536            // total tokens = D*H*W*T
#define SCALE 0.25f
#define LNEPS 1e-5f
// padded spatial geometry for conv
#define PD 18
#define PH 34
#define PW 34
#define PSITES (PD*PH*PW)                // 20808
#define Y1P_SHORTS ((size_t)PSITES*512)  // *4t*128c

__device__ __forceinline__ float b2f(short s) {
  union { unsigned u; float f; } c; c.u = ((unsigned)(unsigned short)s) << 16; return c.f;
}
__device__ __forceinline__ short f2b(float f) {
  __hip_bfloat16 h = __float2bfloat16(f);
  return *reinterpret_cast<short*>(&h);
}
__device__ __forceinline__ float fast_gelu(float x) {
  float u = 1.595769122f * x * fmaf(0.044715f, x*x, 1.0f);
  return x / (1.0f + __expf(-u));
}

__device__ __forceinline__ f32x4 mfma16x16x16_bf16(s16x4 a, s16x4 b, f32x4 c) {
#if __has_builtin(__builtin_amdgcn_mfma_f32_16x16x16_bf16)
  return __builtin_amdgcn_mfma_f32_16x16x16_bf16(a, b, c, 0, 0, 0);
#elif __has_builtin(__builtin_amdgcn_mfma_f32_16x16x16bf16_1k)
  return __builtin_amdgcn_mfma_f32_16x16x16bf16_1k(a, b, c, 0, 0, 0);
#else
  f32x4 d;
  asm("v_mfma_f32_16x16x16_bf16 %0, %1, %2, %3" : "=v"(d) : "v"(a), "v"(b), "v"(c));
  return d;
#endif
}

// async global->LDS, 16B per lane; lds base wave-uniform (HW appends lane*16).
__device__ __forceinline__ void gload16(const short* g, short* l) {
  __builtin_amdgcn_global_load_lds(
      (const __attribute__((address_space(1))) void*)g,
      (__attribute__((address_space(3))) void*)l, 16, 0, 0);
}

// ---------------------------------------------------------------------------
// Kernel 0: weight prep (+ w2f fragment prepack for the fused MLP)
// ---------------------------------------------------------------------------
__global__ void prep_kernel(const float* __restrict__ qkv_w, const float* __restrict__ proj_w,
                            const float* __restrict__ fc1_w, const float* __restrict__ fc2_w,
                            const float* __restrict__ conv_w,
                            __hip_bfloat16* wq, __hip_bfloat16* wp,
                            __hip_bfloat16* w1, __hip_bfloat16* w2f, float* cwT) {
  int idx = blockIdx.x * 256 + threadIdx.x;
  if (idx < 49152) {
    wq[idx] = __float2bfloat16(qkv_w[idx]);
  } else if (idx < 65536) {
    wp[idx - 49152] = __float2bfloat16(proj_w[idx - 49152]);
  } else if (idx < 131072) {
    w1[idx - 65536] = __float2bfloat16(fc1_w[idx - 65536]);
  } else if (idx < 131072 + 27*128) {
    int j = idx - 131072;
    int tap = j >> 7, c = j & 127;
    cwT[tap*128 + c] = conv_w[c*27 + tap];   // (C,1,3,3,3) -> (27,C)
  } else if (idx < 131072 + 3456 + 65536) {
    int j2 = idx - (131072 + 3456);
    int r = j2 & 3, lane = (j2 >> 2) & 63, f = j2 >> 8;
    int fr = lane & 15, kg = lane >> 4;
    int s = f >> 6, jj = (f >> 3) & 7, ct = f & 7;
    w2f[j2] = __float2bfloat16(fc2_w[(ct*16 + fr)*512 + s*128 + jj*16 + kg*4 + r]);
  }
}

// ---------------------------------------------------------------------------
// Kernel: zero only the BORDER sites of the padded y1 buffer (4424 sites).
// ---------------------------------------------------------------------------
__global__ __launch_bounds__(256) void border_zero_kernel(short* __restrict__ y1p) {
  int idx = blockIdx.x*256 + threadIdx.x;
  if (idx >= PSITES*64) return;
  int site = idx >> 6;
  int w = site % PW, hh = (site / PW) % PH, d = site / (PW*PH);
  if (d != 0 && d != PD-1 && hh != 0 && hh != PH-1 && w != 0 && w != PW-1) return;
  *(s16x8*)&y1p[(size_t)site*512 + (idx & 63)*8] = (s16x8)0;
}

// ---------------------------------------------------------------------------
// Kernel 1: LN1 + positional/temporal embed -> window-token layout bf16
// ---------------------------------------------------------------------------
__global__ __launch_bounds__(256) void ln1_pe_kernel(
    const float* __restrict__ x, const float* __restrict__ g, const float* __restrict__ b,
    const float* __restrict__ pos, const float* __restrict__ te,
    __hip_bfloat16* __restrict__ hb) {
  int wv = threadIdx.x >> 6, lane = threadIdx.x & 63;
  int tk = blockIdx.x * 4 + wv;                 // tk = wid*256 + n
  int wid = tk >> 8, n = tk & 255;
  int t = n >> 6, gd = (n >> 4) & 3, gh = (n >> 2) & 3, gw = n & 3;
  int wd = wid >> 6, wh = (wid >> 3) & 7, ww = wid & 7;
  int d = wd*4 + gd, h = wh*4 + gh, w = ww*4 + gw;
  size_t xoff = ((size_t)((d*32 + h)*32 + w)*4 + t) * CC;
  float v0 = x[xoff + lane], v1 = x[xoff + lane + 64];
  float s = v0 + v1, sq = v0*v0 + v1*v1;
  for (int m = 32; m; m >>= 1) { s += __shfl_xor(s, m); sq += __shfl_xor(sq, m); }
  float mean = s * (1.f/128.f);
  float var  = sq * (1.f/128.f) - mean*mean;
  float rstd = rsqrtf(var + LNEPS);
  int pb = ((gd*4 + gh)*4 + gw) * CC, tb = t * CC;
  float h0 = (v0 - mean)*rstd*g[lane]    + b[lane]    + pos[pb + lane]    + te[tb + lane];
  float h1 = (v1 - mean)*rstd*g[lane+64] + b[lane+64] + pos[pb + lane+64] + te[tb + lane+64];
  hb[(size_t)tk*CC + lane]      = __float2bfloat16(h0);
  hb[(size_t)tk*CC + lane + 64] = __float2bfloat16(h1);
}

// ---------------------------------------------------------------------------
// GEMM template (R13): 128x128 tile, BK=64, 4 waves, compile-time K.
// Staging: global_load_lds width=16, LINEAR LDS [128][64].
// MODE 0: qkv split; MODE 1: proj -> PADDED spatial scatter bf16.
// ---------------------------------------------------------------------------
template <int MODE, int KK>
__global__ __launch_bounds__(256) void gemm_kernel(
    const short* __restrict__ Ag, const short* __restrict__ Wg,
    const float* __restrict__ bias, void* __restrict__ out0) {
  __shared__ __align__(16) short As[128*64];
  __shared__ __align__(16) short Bs[128*64];
  const int tid = threadIdx.x;
  const int m0 = blockIdx.x * 128;
  const int n0 = blockIdx.y * 128;
  const int lane = tid & 63, wv = tid >> 6;
  const int wr = wv >> 1, wc = wv & 1;
  const int fr = lane & 15, kg = lane >> 4;

  f32x4 acc[4][4];
#pragma unroll
  for (int i = 0; i < 4; ++i)
#pragma unroll
    for (int j = 0; j < 4; ++j) acc[i][j] = (f32x4)0.f;

#pragma unroll
  for (int kc = 0; kc < KK; kc += 64) {
    __syncthreads();
#pragma unroll
    for (int i = 0; i < 4; ++i) {
      const int e = i*2048 + tid*8;          // short index in 128x64 tile
      const int row = e >> 6, col = e & 63;
      gload16(Ag + (size_t)(m0 + row)*KK + kc + col, &As[i*2048 + wv*512]);
      gload16(Wg + (size_t)(n0 + row)*KK + kc + col, &Bs[i*2048 + wv*512]);
    }
    __syncthreads();
#pragma unroll
    for (int ks = 0; ks < 2; ++ks) {
      s16x8 a[4], b[4];
#pragma unroll
      for (int i = 0; i < 4; ++i)
        a[i] = *(const s16x8*)&As[(wr*64 + i*16 + fr)*64 + ks*32 + kg*8];
#pragma unroll
      for (int j = 0; j < 4; ++j)
        b[j] = *(const s16x8*)&Bs[(wc*64 + j*16 + fr)*64 + ks*32 + kg*8];
#pragma unroll
      for (int i = 0; i < 4; ++i)
#pragma unroll
        for (int j = 0; j < 4; ++j)
          acc[i][j] = __builtin_amdgcn_mfma_f32_16x16x32_bf16(b[j], a[i], acc[i][j], 0, 0, 0);
    }
  }

  const int nbb = n0 + wc*64 + kg*4;
  f32x4 bj4[4];
#pragma unroll
  for (int j = 0; j < 4; ++j) bj4[j] = *(const f32x4*)&bias[nbb + j*16];

#pragma unroll
  for (int i = 0; i < 4; ++i) {
    const int m = m0 + wr*64 + i*16 + fr;
    if constexpr (MODE == 0) {
      short* qs = (short*)out0;
      const int sec = n0 >> 7;
      const float scl = (sec == 0) ? SCALE : 1.0f;
      const int wid = m >> 8, ntok = m & 255;
      const int rowbase = sec*8388608 + (wid*8)*4096 + ntok*16 + (nbb & 15);
#pragma unroll
      for (int j = 0; j < 4; ++j) {
        const int head = ((nbb + j*16) >> 4) & 7;
        f32x4 v = acc[i][j];
        s16x4 o;
        o[0] = f2b(fmaf(v[0], scl, bj4[j].x*scl));
        o[1] = f2b(fmaf(v[1], scl, bj4[j].y*scl));
        o[2] = f2b(fmaf(v[2], scl, bj4[j].z*scl));
        o[3] = f2b(fmaf(v[3], scl, bj4[j].w*scl));
        *(s16x4*)&qs[rowbase + head*4096] = o;
      }
    } else {
      short* y1o = (short*)out0;       // PADDED [18][34][34][4][128]
      const int wid = m >> 8, ntok = m & 255;
      const int t = ntok >> 6, gd = (ntok >> 4) & 3, gh = (ntok >> 2) & 3, gw = ntok & 3;
      const int wd = wid >> 6, wh = (wid >> 3) & 7, ww = wid & 7;
      const int sr = (((wd*4 + gd + 1)*PH + wh*4 + gh + 1)*PW + ww*4 + gw + 1)*4 + t;
      const int base = sr*CC + nbb;
#pragma unroll
      for (int j = 0; j < 4; ++j) {
        f32x4 v = acc[i][j];
        s16x4 o;
        o[0] = f2b(v[0] + bj4[j].x); o[1] = f2b(v[1] + bj4[j].y);
        o[2] = f2b(v[2] + bj4[j].z); o[3] = f2b(v[3] + bj4[j].w);
        *(s16x4*)&y1o[base + j*16] = o;
      }
    }
  }
}

// ---------------------------------------------------------------------------
// Kernel: FUSED MLP v3 — out = gelu(h2 @ w1^T + b1) @ w2^T + b2 + resid.
// BM=64: 1024 blocks x 4 waves; wave owns 16 rows. LDS 32KB:
// As = 2x[64][64] (h2, staged once), Ws = [128][64] (w1 slice, re-staged per
// (s,half)) -> ~3 blocks/CU resident (was <2 at 48KB/128-row in R16).
// GEMM2: gelu+cvt in-register; w2 fragments read coalesced from prepacked w2f.
// Same accumulation order as R16 -> bit-identical output.
// ---------------------------------------------------------------------------
__global__ __launch_bounds__(256) void mlp_kernel(
    const short* __restrict__ h2, const short* __restrict__ w1,
    const short* __restrict__ w2f, const float* __restrict__ b1,
    const float* __restrict__ b2, const _Float16* __restrict__ resid,
    float* __restrict__ out) {
  __shared__ __align__(16) short As[2][64*64];
  __shared__ __align__(16) short Ws[128*64];
  const int tid = threadIdx.x;
  const int m0 = blockIdx.x * 64;
  const int lane = tid & 63, wv = tid >> 6;
  const int fr = lane & 15, kg = lane >> 4;

  // stage h2 tile (both K-halves) once: [64][64] per half = 2 chunks each
#pragma unroll
  for (int half = 0; half < 2; ++half)
#pragma unroll
    for (int i = 0; i < 2; ++i) {
      const int e = i*2048 + tid*8;
      const int row = e >> 6, col = e & 63;
      gload16(h2 + (size_t)(m0 + row)*128 + half*64 + col, &As[half][i*2048 + wv*512]);
    }

  f32x4 acc2[8];
#pragma unroll
  for (int c = 0; c < 8; ++c) acc2[c] = (f32x4)0.f;

#pragma unroll
  for (int s = 0; s < 4; ++s) {
    f32x4 acc1[8];
#pragma unroll
    for (int j = 0; j < 8; ++j) acc1[j] = (f32x4)0.f;

#pragma unroll
    for (int half = 0; half < 2; ++half) {
      __syncthreads();                    // Ws readers of prev round done
#pragma unroll
      for (int i = 0; i < 4; ++i) {
        const int e = i*2048 + tid*8;
        const int row = e >> 6, col = e & 63;
        gload16(w1 + (size_t)(s*128 + row)*128 + half*64 + col, &Ws[i*2048 + wv*512]);
      }
      __syncthreads();                    // drains Ws (+As on first pass)
#pragma unroll
      for (int ks = 0; ks < 2; ++ks) {
        s16x8 a = *(const s16x8*)&As[half][(wv*16 + fr)*64 + ks*32 + kg*8];
        s16x8 b[8];
#pragma unroll
        for (int j = 0; j < 8; ++j)
          b[j] = *(const s16x8*)&Ws[(j*16 + fr)*64 + ks*32 + kg*8];
#pragma unroll
        for (int j = 0; j < 8; ++j)
          acc1[j] = __builtin_amdgcn_mfma_f32_16x16x32_bf16(b[j], a, acc1[j], 0, 0, 0);
      }
    }

    // GEMM2: gelu+cvt in-register; D^T frag (lane holds h1[m=fr][k=kg*4+r])
    // IS the 16x16x16 A-operand. w2f fragment loads are coalesced 512B.
#pragma unroll
    for (int j = 0; j < 8; ++j) {
      f32x4 b1v = *(const f32x4*)&b1[s*128 + j*16 + kg*4];
      f32x4 v = acc1[j];
      s16x4 pa;
      pa[0] = f2b(fast_gelu(v[0] + b1v.x));
      pa[1] = f2b(fast_gelu(v[1] + b1v.y));
      pa[2] = f2b(fast_gelu(v[2] + b1v.z));
      pa[3] = f2b(fast_gelu(v[3] + b1v.w));
      const int fb = ((s*8 + j)*8)*256 + lane*4;
#pragma unroll
      for (int ct = 0; ct < 8; ++ct) {
        s16x4 wf = *(const s16x4*)&w2f[fb + ct*256];
        acc2[ct] = mfma16x16x16_bf16(wf, pa, acc2[ct]);
      }
    }
  }

  // epilogue: out[m][c] = acc2 + b2 + resid (fp16), c = ct*16 + kg*4 + r
  const int m = m0 + wv*16 + fr;
#pragma unroll
  for (int ct = 0; ct < 8; ++ct) {
    const int c = ct*16 + kg*4;
    const int base = m*CC + c;
    f32x4 b2v = *(const f32x4*)&b2[c];
    f16x4 rz = *(const f16x4*)&resid[base];
    f32x4 v = acc2[ct];
    f32x4 o;
    o.x = v[0] + b2v.x + (float)rz[0];
    o.y = v[1] + b2v.y + (float)rz[1];
    o.z = v[2] + b2v.z + (float)rz[2];
    o.w = v[3] + b2v.w + (float)rz[3];
    *(f32x4*)&out[base] = o;
  }
}

// ---------------------------------------------------------------------------
// Kernel: MFMA window attention (unchanged from R2).
// ---------------------------------------------------------------------------
#define KPAD 20
#define VPAD 264
__global__ __launch_bounds__(256) void attn_mfma_kernel(
    const __hip_bfloat16* __restrict__ qb, const __hip_bfloat16* __restrict__ kb,
    const __hip_bfloat16* __restrict__ vb, __hip_bfloat16* __restrict__ ob) {
  __shared__ __align__(16) short kL[256*KPAD];
  __shared__ __align__(16) short vT[16*VPAD];
  const int bh = blockIdx.x;                // win*8 + head
  const int wid = bh >> 3, head = bh & 7;
  const int tid = threadIdx.x;
  const short* kg = (const short*)kb + (size_t)bh*4096;
  const short* vg = (const short*)vb + (size_t)bh*4096;
  const short* qg = (const short*)qb + (size_t)bh*4096;
  {
    s16x8 a0 = *(const s16x8*)&kg[tid*16];
    s16x8 a1 = *(const s16x8*)&kg[tid*16 + 8];
    *(s16x8*)&kL[tid*KPAD]     = a0;
    *(s16x8*)&kL[tid*KPAD + 8] = a1;
    s16x8 b0 = *(const s16x8*)&vg[tid*16];
    s16x8 b1 = *(const s16x8*)&vg[tid*16 + 8];
#pragma unroll
    for (int d = 0; d < 8; ++d) {
      vT[d*VPAD + tid]     = b0[d];
      vT[(d+8)*VPAD + tid] = b1[d];
    }
  }
  __syncthreads();
  const int wv = tid >> 6, lane = tid & 63;
  const int fr = lane & 15, hi = lane >> 4;
  s16x4 kfrag[16], vfrag[16];
#pragma unroll
  for (int t = 0; t < 16; ++t) {
    kfrag[t] = *(const s16x4*)&kL[(t*16 + fr)*KPAD + hi*4];
    vfrag[t] = *(const s16x4*)&vT[fr*VPAD + t*16 + hi*4];
  }
  short* obs = (short*)ob;
  for (int qt = 0; qt < 4; ++qt) {
    const int q0 = wv*64 + qt*16;
    s16x4 qfrag = *(const s16x4*)&qg[(q0 + fr)*16 + hi*4];
    f32x4 st[16];
#pragma unroll
    for (int kt = 0; kt < 16; ++kt)
      st[kt] = mfma16x16x16_bf16(kfrag[kt], qfrag, (f32x4)0.f);
    float den = 0.f;
    f32x4 oacc = (f32x4)0.f;
#pragma unroll
    for (int kt = 0; kt < 16; ++kt) {
      float e0 = __expf(st[kt][0]), e1 = __expf(st[kt][1]);
      float e2 = __expf(st[kt][2]), e3 = __expf(st[kt][3]);
      den += (e0 + e1) + (e2 + e3);
      s16x4 pa;
      pa[0] = f2b(e0); pa[1] = f2b(e1); pa[2] = f2b(e2); pa[3] = f2b(e3);
      oacc = mfma16x16x16_bf16(vfrag[kt], pa, oacc);
    }
    den += __shfl_xor(den, 16);
    den += __shfl_xor(den, 32);
    float inv = 1.f / den;
    s16x4 ov;
    ov[0] = f2b(oacc[0]*inv); ov[1] = f2b(oacc[1]*inv);
    ov[2] = f2b(oacc[2]*inv); ov[3] = f2b(oacc[3]*inv);
    *(s16x4*)&obs[((size_t)wid*256 + q0 + fr)*CC + head*16 + hi*4] = ov;
  }
}

// ---------------------------------------------------------------------------
// Kernel: FUSED conv3x3x3 (padded bf16 in, NO guards) + exln + norm2.
// R8's proven structure: thread = (site, c8-group), 4 independent t-chains.
// ---------------------------------------------------------------------------
__global__ __launch_bounds__(256) void conv_ln_kernel(
    const __hip_bfloat16* __restrict__ y1p, const float* __restrict__ wT,
    const float* __restrict__ cb,
    const float* __restrict__ exg, const float* __restrict__ exb,
    const float* __restrict__ n2g, const float* __restrict__ n2b,
    _Float16* __restrict__ yb, __hip_bfloat16* __restrict__ h2) {
  const int tid = threadIdx.x;
  const int sp = blockIdx.x*16 + (tid >> 4);     // spatial site 0..16383
  const int cbase = (tid & 15) * 8;              // 8-channel group
  const int w = sp & 31, h = (sp >> 5) & 31, d = sp >> 10;
  const int psite = ((d+1)*PH + (h+1))*PW + (w+1);
  const short* base = (const short*)y1p + (size_t)psite*512 + cbase;

  float acc[4][8];
  {
    f32x4 cb0 = *(const f32x4*)&cb[cbase];
    f32x4 cb1 = *(const f32x4*)&cb[cbase + 4];
#pragma unroll
    for (int t = 0; t < 4; ++t) {
      acc[t][0]=cb0.x; acc[t][1]=cb0.y; acc[t][2]=cb0.z; acc[t][3]=cb0.w;
      acc[t][4]=cb1.x; acc[t][5]=cb1.y; acc[t][6]=cb1.z; acc[t][7]=cb1.w;
    }
  }

#pragma unroll
  for (int dd = -1; dd <= 1; ++dd)
#pragma unroll
    for (int dh = -1; dh <= 1; ++dh)
#pragma unroll
      for (int dw = -1; dw <= 1; ++dw) {
        const int tap = ((dd+1)*3 + (dh+1))*3 + (dw+1);
        const int toff = ((dd*PH + dh)*PW + dw)*512;
        f32x4 w0 = *(const f32x4*)&wT[tap*CC + cbase];
        f32x4 w1 = *(const f32x4*)&wT[tap*CC + cbase + 4];
#pragma unroll
        for (int t = 0; t < 4; ++t) {
          s16x8 v = *(const s16x8*)(base + toff + t*CC);
          acc[t][0] = fmaf(b2f(v[0]), w0.x, acc[t][0]);
          acc[t][1] = fmaf(b2f(v[1]), w0.y, acc[t][1]);
          acc[t][2] = fmaf(b2f(v[2]), w0.z, acc[t][2]);
          acc[t][3] = fmaf(b2f(v[3]), w0.w, acc[t][3]);
          acc[t][4] = fmaf(b2f(v[4]), w1.x, acc[t][4]);
          acc[t][5] = fmaf(b2f(v[5]), w1.y, acc[t][5]);
          acc[t][6] = fmaf(b2f(v[6]), w1.z, acc[t][6]);
          acc[t][7] = fmaf(b2f(v[7]), w1.w, acc[t][7]);
        }
      }

  f32x4 eg0 = *(const f32x4*)&exg[cbase], eg1 = *(const f32x4*)&exg[cbase+4];
  f32x4 eb0 = *(const f32x4*)&exb[cbase], eb1 = *(const f32x4*)&exb[cbase+4];
  f32x4 ng0 = *(const f32x4*)&n2g[cbase], ng1 = *(const f32x4*)&n2g[cbase+4];
  f32x4 nb0 = *(const f32x4*)&n2b[cbase], nb1 = *(const f32x4*)&n2b[cbase+4];
  float eg[8] = {eg0.x,eg0.y,eg0.z,eg0.w,eg1.x,eg1.y,eg1.z,eg1.w};
  float eb[8] = {eb0.x,eb0.y,eb0.z,eb0.w,eb1.x,eb1.y,eb1.z,eb1.w};
  float ng[8] = {ng0.x,ng0.y,ng0.z,ng0.w,ng1.x,ng1.y,ng1.z,ng1.w};
  float nb[8] = {nb0.x,nb0.y,nb0.z,nb0.w,nb1.x,nb1.y,nb1.z,nb1.w};

#pragma unroll
  for (int t = 0; t < 4; ++t) {
    float s = 0.f, sq = 0.f;
#pragma unroll
    for (int c = 0; c < 8; ++c) { s += acc[t][c]; sq = fmaf(acc[t][c], acc[t][c], sq); }
#pragma unroll
    for (int m = 1; m <= 8; m <<= 1) { s += __shfl_xor(s, m); sq += __shfl_xor(sq, m); }
    float mean = s * (1.f/128.f);
    float var  = sq * (1.f/128.f) - mean*mean;
    float rstd = rsqrtf(var + LNEPS);
    float y[8];
    f16x8 yo;
#pragma unroll
    for (int c = 0; c < 8; ++c) {
      y[c] = (acc[t][c] - mean)*rstd*eg[c] + eb[c];
      yo[c] = (_Float16)y[c];
    }
    *(f16x8*)&yb[(size_t)(sp*4 + t)*CC + cbase] = yo;
    float s2 = 0.f, sq2 = 0.f;
#pragma unroll
    for (int c = 0; c < 8; ++c) { s2 += y[c]; sq2 = fmaf(y[c], y[c], sq2); }
#pragma unroll
    for (int m = 1; m <= 8; m <<= 1) { s2 += __shfl_xor(s2, m); sq2 += __shfl_xor(sq2, m); }
    float mean2 = s2 * (1.f/128.f);
    float var2  = sq2 * (1.f/128.f) - mean2*mean2;
    float rstd2 = rsqrtf(var2 + LNEPS);
    s16x8 ho;
#pragma unroll
    for (int c = 0; c < 8; ++c)
      ho[c] = f2b((y[c] - mean2)*rstd2*ng[c] + nb[c]);
    *(s16x8*)&((short*)h2)[(size_t)(sp*4 + t)*CC + cbase] = ho;
  }
}

// ---------------------------------------------------------------------------
// Launch
// ---------------------------------------------------------------------------
extern "C" void kernel_launch(void* const* d_in, const int* in_sizes, int n_in,
                              void* d_out, int out_size, void* d_ws, size_t ws_size,
                              hipStream_t stream) {
  const float* x      = (const float*)d_in[0];
  const float* n1g    = (const float*)d_in[1];
  const float* n1b    = (const float*)d_in[2];
  const float* pos    = (const float*)d_in[3];
  const float* te     = (const float*)d_in[4];
  const float* qkv_w  = (const float*)d_in[5];
  const float* qkv_b  = (const float*)d_in[6];
  const float* proj_w = (const float*)d_in[7];
  const float* proj_b = (const float*)d_in[8];
  const float* conv_w = (const float*)d_in[9];
  const float* conv_b = (const float*)d_in[10];
  const float* exg    = (const float*)d_in[11];
  const float* exb    = (const float*)d_in[12];
  const float* n2g    = (const float*)d_in[13];
  const float* n2b    = (const float*)d_in[14];
  const float* fc1_w  = (const float*)d_in[15];
  const float* fc1_b  = (const float*)d_in[16];
  const float* fc2_w  = (const float*)d_in[17];
  const float* fc2_b  = (const float*)d_in[18];

  char* wsb = (char*)d_ws;
  __hip_bfloat16* wq  = (__hip_bfloat16*)(wsb);             // 384x128
  __hip_bfloat16* wp  = (__hip_bfloat16*)(wsb + 98304);     // 128x128
  __hip_bfloat16* w1  = (__hip_bfloat16*)(wsb + 131072);    // 512x128
  float*          cwT = (float*)(wsb + 262144);             // 27x128 (13824B)
  __hip_bfloat16* w2f = (__hip_bfloat16*)(wsb + 276480);    // 256 frags x 256 (128KB)

  const size_t A_OFF = (size_t)1 << 20;                     // 16 MiB region
  const size_t B_OFF = A_OFF + ((size_t)16 << 20);          // 48 MiB region

  __hip_bfloat16* hbuf = (__hip_bfloat16*)(wsb + A_OFF);    // LN1 out
  __hip_bfloat16* obuf = (__hip_bfloat16*)(wsb + A_OFF);    // attn out (reuses A)
  __hip_bfloat16* h2in = (__hip_bfloat16*)(wsb + A_OFF);    // MLP in (reuses A)
  __hip_bfloat16* qkvb = (__hip_bfloat16*)(wsb + B_OFF);    // q|k|v, 16MiB each
  __hip_bfloat16* qb   = qkvb;
  __hip_bfloat16* kb   = qkvb + 8388608;
  __hip_bfloat16* vb   = qkvb + 16777216;
  __hip_bfloat16* y1p  = (__hip_bfloat16*)(wsb + B_OFF);    // padded proj out (20.3 MiB)
  _Float16* yb = (_Float16*)(wsb + B_OFF + ((size_t)24 << 20)); // fp16 y (16 MiB)

  prep_kernel<<<782, 256, 0, stream>>>(qkv_w, proj_w, fc1_w, fc2_w, conv_w,
                                       wq, wp, w1, w2f, cwT);
  ln1_pe_kernel<<<TOKS/4, 256, 0, stream>>>(x, n1g, n1b, pos, te, hbuf);
  gemm_kernel<0, 128><<<dim3(TOKS/128, 3), 256, 0, stream>>>(
      (const short*)hbuf, (const short*)wq, qkv_b, (void*)qkvb);
  attn_mfma_kernel<<<NWIN*8, 256, 0, stream>>>(qb, kb, vb, obuf);
  border_zero_kernel<<<(PSITES*64 + 255)/256, 256, 0, stream>>>((short*)y1p);
  gemm_kernel<1, 128><<<dim3(TOKS/128, 1), 256, 0, stream>>>(
      (const short*)obuf, (const short*)wp, proj_b, (void*)y1p);
  conv_ln_kernel<<<16384/16, 256, 0, stream>>>(y1p, cwT, conv_b,
      exg, exb, n2g, n2b, yb, h2in);
  mlp_kernel<<<TOKS/64, 256, 0, stream>>>(
      (const short*)h2in, (const short*)w1, (const short*)w2f,
      fc1_b, fc2_b, yb, (float*)d_out);
}

// Round 18
// 171.256 us; speedup vs baseline: 1.3327x; 1.1046x over previous
//
#include <hip/hip_runtime.h>
#include <hip/hip_bf16.h>

// ---------------------------------------------------------------------------
// CrossFormerBlock on MI355X (gfx950)
// B=1 D=16 H=32 W=32 T=4 C=128, G=4, NH=8, HD=16, NW=256 windows, N=256 tok/win
// R18: REVERT to R13 (best measured, 173.6us): split fc1/fc2, BK=64 GEMMs with
// global_load_lds staging. Fused-MLP abandoned after 3 attempts (R15/16/17:
// 113/95/74us vs split ~42us — GEMM2 fragment deps can't be hidden in a
// 2-barrier loop). New: ln1_pe vectorized (32 lanes/token, f32x4 loads).
// ---------------------------------------------------------------------------

typedef __attribute__((ext_vector_type(8))) short  s16x8;
typedef __attribute__((ext_vector_type(4))) short  s16x4;
typedef __attribute__((ext_vector_type(4))) float  f32x4;
typedef __attribute__((ext_vector_type(8))) _Float16 f16x8;
typedef __attribute__((ext_vector_type(4))) _Float16 f16x4;

#define CC    128
#define NWIN  256
#define TOKS  65536            // total tokens = D*H*W*T
#define SCALE 0.25f
#define LNEPS 1e-5f
// padded spatial geometry for conv
#define PD 18
#define PH 34
#define PW 34
#define PSITES (PD*PH*PW)                // 20808
#define Y1P_SHORTS ((size_t)PSITES*512)  // *4t*128c

__device__ __forceinline__ float b2f(short s) {
  union { unsigned u; float f; } c; c.u = ((unsigned)(unsigned short)s) << 16; return c.f;
}
__device__ __forceinline__ short f2b(float f) {
  __hip_bfloat16 h = __float2bfloat16(f);
  return *reinterpret_cast<short*>(&h);
}
__device__ __forceinline__ float fast_gelu(float x) {
  float u = 1.595769122f * x * fmaf(0.044715f, x*x, 1.0f);
  return x / (1.0f + __expf(-u));
}

__device__ __forceinline__ f32x4 mfma16x16x16_bf16(s16x4 a, s16x4 b, f32x4 c) {
#if __has_builtin(__builtin_amdgcn_mfma_f32_16x16x16_bf16)
  return __builtin_amdgcn_mfma_f32_16x16x16_bf16(a, b, c, 0, 0, 0);
#elif __has_builtin(__builtin_amdgcn_mfma_f32_16x16x16bf16_1k)
  return __builtin_amdgcn_mfma_f32_16x16x16bf16_1k(a, b, c, 0, 0, 0);
#else
  f32x4 d;
  asm("v_mfma_f32_16x16x16_bf16 %0, %1, %2, %3" : "=v"(d) : "v"(a), "v"(b), "v"(c));
  return d;
#endif
}

// async global->LDS, 16B per lane; lds base wave-uniform (HW appends lane*16).
__device__ __forceinline__ void gload16(const short* g, short* l) {
  __builtin_amdgcn_global_load_lds(
      (const __attribute__((address_space(1))) void*)g,
      (__attribute__((address_space(3))) void*)l, 16, 0, 0);
}

// ---------------------------------------------------------------------------
// Kernel 0: weight prep
// ---------------------------------------------------------------------------
__global__ void prep_kernel(const float* __restrict__ qkv_w, const float* __restrict__ proj_w,
                            const float* __restrict__ fc1_w, const float* __restrict__ fc2_w,
                            const float* __restrict__ conv_w,
                            __hip_bfloat16* wq, __hip_bfloat16* wp,
                            __hip_bfloat16* w1, __hip_bfloat16* w2, float* cwT) {
  int idx = blockIdx.x * 256 + threadIdx.x;
  if (idx < 49152) {
    wq[idx] = __float2bfloat16(qkv_w[idx]);
  } else if (idx < 65536) {
    wp[idx - 49152] = __float2bfloat16(proj_w[idx - 49152]);
  } else if (idx < 131072) {
    w1[idx - 65536] = __float2bfloat16(fc1_w[idx - 65536]);
  } else if (idx < 196608) {
    w2[idx - 131072] = __float2bfloat16(fc2_w[idx - 131072]);
  } else if (idx < 196608 + 27*128) {
    int j = idx - 196608;
    int tap = j >> 7, c = j & 127;
    cwT[tap*128 + c] = conv_w[c*27 + tap];   // (C,1,3,3,3) -> (27,C)
  }
}

// ---------------------------------------------------------------------------
// Kernel: zero only the BORDER sites of the padded y1 buffer (4424 sites).
// ---------------------------------------------------------------------------
__global__ __launch_bounds__(256) void border_zero_kernel(short* __restrict__ y1p) {
  int idx = blockIdx.x*256 + threadIdx.x;
  if (idx >= PSITES*64) return;
  int site = idx >> 6;
  int w = site % PW, hh = (site / PW) % PH, d = site / (PW*PH);
  if (d != 0 && d != PD-1 && hh != 0 && hh != PH-1 && w != 0 && w != PW-1) return;
  *(s16x8*)&y1p[(size_t)site*512 + (idx & 63)*8] = (s16x8)0;
}

// ---------------------------------------------------------------------------
// Kernel 1: LN1 + positional/temporal embed -> window-token layout bf16.
// R18: vectorized — 32 lanes/token, f32x4 loads (16B/lane), LN via 5x
// shfl_xor over the 32-lane channel group, s16x4 stores.
// ---------------------------------------------------------------------------
__global__ __launch_bounds__(256) void ln1_pe_kernel(
    const float* __restrict__ x, const float* __restrict__ g, const float* __restrict__ b,
    const float* __restrict__ pos, const float* __restrict__ te,
    __hip_bfloat16* __restrict__ hb) {
  const int tid = threadIdx.x;
  const int tk = blockIdx.x*8 + (tid >> 5);     // token = wid*256 + n
  const int c4 = (tid & 31) * 4;
  const int wid = tk >> 8, n = tk & 255;
  const int t = n >> 6, gd = (n >> 4) & 3, gh = (n >> 2) & 3, gw = n & 3;
  const int wd = wid >> 6, wh = (wid >> 3) & 7, ww = wid & 7;
  const int d = wd*4 + gd, h = wh*4 + gh, w = ww*4 + gw;
  const size_t xoff = ((size_t)((d*32 + h)*32 + w)*4 + t) * CC;
  f32x4 v = *(const f32x4*)&x[xoff + c4];
  float s  = (v.x + v.y) + (v.z + v.w);
  float sq = (v.x*v.x + v.y*v.y) + (v.z*v.z + v.w*v.w);
#pragma unroll
  for (int m = 1; m <= 16; m <<= 1) { s += __shfl_xor(s, m); sq += __shfl_xor(sq, m); }
  const float mean = s * (1.f/128.f);
  const float var  = sq * (1.f/128.f) - mean*mean;
  const float rstd = rsqrtf(var + LNEPS);
  const int pb = ((gd*4 + gh)*4 + gw) * CC, tb = t * CC;
  f32x4 gv = *(const f32x4*)&g[c4];
  f32x4 bv = *(const f32x4*)&b[c4];
  f32x4 pv = *(const f32x4*)&pos[pb + c4];
  f32x4 tv = *(const f32x4*)&te[tb + c4];
  s16x4 o;
  o[0] = f2b((v.x - mean)*rstd*gv.x + bv.x + pv.x + tv.x);
  o[1] = f2b((v.y - mean)*rstd*gv.y + bv.y + pv.y + tv.y);
  o[2] = f2b((v.z - mean)*rstd*gv.z + bv.z + pv.z + tv.z);
  o[3] = f2b((v.w - mean)*rstd*gv.w + bv.w + pv.w + tv.w);
  *(s16x4*)&((short*)hb)[(size_t)tk*CC + c4] = o;
}

// ---------------------------------------------------------------------------
// GEMM template (R13): 128x128 tile, BK=64, 4 waves, compile-time K.
// Staging: global_load_lds width=16, LINEAR LDS [128][64].
// MODE 0: qkv split; MODE 1: proj -> PADDED spatial scatter bf16;
// MODE 2: fc1 + fast GELU; MODE 3: fc2 + bias + fp16 residual -> fp32 d_out
// ---------------------------------------------------------------------------
template <int MODE, int KK>
__global__ __launch_bounds__(256) void gemm_kernel(
    const short* __restrict__ Ag, const short* __restrict__ Wg,
    const float* __restrict__ bias,
    void* __restrict__ out0, const _Float16* __restrict__ resid) {
  __shared__ __align__(16) short As[128*64];
  __shared__ __align__(16) short Bs[128*64];
  const int tid = threadIdx.x;
  const int m0 = blockIdx.x * 128;
  const int n0 = blockIdx.y * 128;
  const int lane = tid & 63, wv = tid >> 6;
  const int wr = wv >> 1, wc = wv & 1;
  const int fr = lane & 15, kg = lane >> 4;

  f32x4 acc[4][4];
#pragma unroll
  for (int i = 0; i < 4; ++i)
#pragma unroll
    for (int j = 0; j < 4; ++j) acc[i][j] = (f32x4)0.f;

#pragma unroll
  for (int kc = 0; kc < KK; kc += 64) {
    __syncthreads();
#pragma unroll
    for (int i = 0; i < 4; ++i) {
      const int e = i*2048 + tid*8;          // short index in 128x64 tile
      const int row = e >> 6, col = e & 63;
      gload16(Ag + (size_t)(m0 + row)*KK + kc + col, &As[i*2048 + wv*512]);
      gload16(Wg + (size_t)(n0 + row)*KK + kc + col, &Bs[i*2048 + wv*512]);
    }
    __syncthreads();
#pragma unroll
    for (int ks = 0; ks < 2; ++ks) {
      s16x8 a[4], b[4];
#pragma unroll
      for (int i = 0; i < 4; ++i)
        a[i] = *(const s16x8*)&As[(wr*64 + i*16 + fr)*64 + ks*32 + kg*8];
#pragma unroll
      for (int j = 0; j < 4; ++j)
        b[j] = *(const s16x8*)&Bs[(wc*64 + j*16 + fr)*64 + ks*32 + kg*8];
#pragma unroll
      for (int i = 0; i < 4; ++i)
#pragma unroll
        for (int j = 0; j < 4; ++j)
          acc[i][j] = __builtin_amdgcn_mfma_f32_16x16x32_bf16(b[j], a[i], acc[i][j], 0, 0, 0);
    }
  }

  const int nbb = n0 + wc*64 + kg*4;
  f32x4 bj4[4];
#pragma unroll
  for (int j = 0; j < 4; ++j) bj4[j] = *(const f32x4*)&bias[nbb + j*16];

#pragma unroll
  for (int i = 0; i < 4; ++i) {
    const int m = m0 + wr*64 + i*16 + fr;
    if constexpr (MODE == 0) {
      short* qs = (short*)out0;
      const int sec = n0 >> 7;
      const float scl = (sec == 0) ? SCALE : 1.0f;
      const int wid = m >> 8, ntok = m & 255;
      const int rowbase = sec*8388608 + (wid*8)*4096 + ntok*16 + (nbb & 15);
#pragma unroll
      for (int j = 0; j < 4; ++j) {
        const int head = ((nbb + j*16) >> 4) & 7;
        f32x4 v = acc[i][j];
        s16x4 o;
        o[0] = f2b(fmaf(v[0], scl, bj4[j].x*scl));
        o[1] = f2b(fmaf(v[1], scl, bj4[j].y*scl));
        o[2] = f2b(fmaf(v[2], scl, bj4[j].z*scl));
        o[3] = f2b(fmaf(v[3], scl, bj4[j].w*scl));
        *(s16x4*)&qs[rowbase + head*4096] = o;
      }
    } else if constexpr (MODE == 1) {
      short* y1o = (short*)out0;       // PADDED [18][34][34][4][128]
      const int wid = m >> 8, ntok = m & 255;
      const int t = ntok >> 6, gd = (ntok >> 4) & 3, gh = (ntok >> 2) & 3, gw = ntok & 3;
      const int wd = wid >> 6, wh = (wid >> 3) & 7, ww = wid & 7;
      const int sr = (((wd*4 + gd + 1)*PH + wh*4 + gh + 1)*PW + ww*4 + gw + 1)*4 + t;
      const int base = sr*CC + nbb;
#pragma unroll
      for (int j = 0; j < 4; ++j) {
        f32x4 v = acc[i][j];
        s16x4 o;
        o[0] = f2b(v[0] + bj4[j].x); o[1] = f2b(v[1] + bj4[j].y);
        o[2] = f2b(v[2] + bj4[j].z); o[3] = f2b(v[3] + bj4[j].w);
        *(s16x4*)&y1o[base + j*16] = o;
      }
    } else if constexpr (MODE == 2) {
      short* gp = (short*)out0;
      const int base = m*512 + nbb;
#pragma unroll
      for (int j = 0; j < 4; ++j) {
        f32x4 v = acc[i][j];
        s16x4 o;
        o[0] = f2b(fast_gelu(v[0] + bj4[j].x)); o[1] = f2b(fast_gelu(v[1] + bj4[j].y));
        o[2] = f2b(fast_gelu(v[2] + bj4[j].z)); o[3] = f2b(fast_gelu(v[3] + bj4[j].w));
        *(s16x4*)&gp[base + j*16] = o;
      }
    } else {
      float* outp = (float*)out0;
      const int base = m*CC + nbb;
#pragma unroll
      for (int j = 0; j < 4; ++j) {
        f32x4 v = acc[i][j];
        f16x4 rz = *(const f16x4*)&resid[base + j*16];
        f32x4 o;
        o.x = v[0] + bj4[j].x + (float)rz[0]; o.y = v[1] + bj4[j].y + (float)rz[1];
        o.z = v[2] + bj4[j].z + (float)rz[2]; o.w = v[3] + bj4[j].w + (float)rz[3];
        *(f32x4*)&outp[base + j*16] = o;
      }
    }
  }
}

// ---------------------------------------------------------------------------
// Kernel: MFMA window attention (unchanged from R2).
// ---------------------------------------------------------------------------
#define KPAD 20
#define VPAD 264
__global__ __launch_bounds__(256) void attn_mfma_kernel(
    const __hip_bfloat16* __restrict__ qb, const __hip_bfloat16* __restrict__ kb,
    const __hip_bfloat16* __restrict__ vb, __hip_bfloat16* __restrict__ ob) {
  __shared__ __align__(16) short kL[256*KPAD];
  __shared__ __align__(16) short vT[16*VPAD];
  const int bh = blockIdx.x;                // win*8 + head
  const int wid = bh >> 3, head = bh & 7;
  const int tid = threadIdx.x;
  const short* kg = (const short*)kb + (size_t)bh*4096;
  const short* vg = (const short*)vb + (size_t)bh*4096;
  const short* qg = (const short*)qb + (size_t)bh*4096;
  {
    s16x8 a0 = *(const s16x8*)&kg[tid*16];
    s16x8 a1 = *(const s16x8*)&kg[tid*16 + 8];
    *(s16x8*)&kL[tid*KPAD]     = a0;
    *(s16x8*)&kL[tid*KPAD + 8] = a1;
    s16x8 b0 = *(const s16x8*)&vg[tid*16];
    s16x8 b1 = *(const s16x8*)&vg[tid*16 + 8];
#pragma unroll
    for (int d = 0; d < 8; ++d) {
      vT[d*VPAD + tid]     = b0[d];
      vT[(d+8)*VPAD + tid] = b1[d];
    }
  }
  __syncthreads();
  const int wv = tid >> 6, lane = tid & 63;
  const int fr = lane & 15, hi = lane >> 4;
  s16x4 kfrag[16], vfrag[16];
#pragma unroll
  for (int t = 0; t < 16; ++t) {
    kfrag[t] = *(const s16x4*)&kL[(t*16 + fr)*KPAD + hi*4];
    vfrag[t] = *(const s16x4*)&vT[fr*VPAD + t*16 + hi*4];
  }
  short* obs = (short*)ob;
  for (int qt = 0; qt < 4; ++qt) {
    const int q0 = wv*64 + qt*16;
    s16x4 qfrag = *(const s16x4*)&qg[(q0 + fr)*16 + hi*4];
    f32x4 st[16];
#pragma unroll
    for (int kt = 0; kt < 16; ++kt)
      st[kt] = mfma16x16x16_bf16(kfrag[kt], qfrag, (f32x4)0.f);
    float den = 0.f;
    f32x4 oacc = (f32x4)0.f;
#pragma unroll
    for (int kt = 0; kt < 16; ++kt) {
      float e0 = __expf(st[kt][0]), e1 = __expf(st[kt][1]);
      float e2 = __expf(st[kt][2]), e3 = __expf(st[kt][3]);
      den += (e0 + e1) + (e2 + e3);
      s16x4 pa;
      pa[0] = f2b(e0); pa[1] = f2b(e1); pa[2] = f2b(e2); pa[3] = f2b(e3);
      oacc = mfma16x16x16_bf16(vfrag[kt], pa, oacc);
    }
    den += __shfl_xor(den, 16);
    den += __shfl_xor(den, 32);
    float inv = 1.f / den;
    s16x4 ov;
    ov[0] = f2b(oacc[0]*inv); ov[1] = f2b(oacc[1]*inv);
    ov[2] = f2b(oacc[2]*inv); ov[3] = f2b(oacc[3]*inv);
    *(s16x4*)&obs[((size_t)wid*256 + q0 + fr)*CC + head*16 + hi*4] = ov;
  }
}

// ---------------------------------------------------------------------------
// Kernel: FUSED conv3x3x3 (padded bf16 in, NO guards) + exln + norm2.
// R8's proven structure: thread = (site, c8-group), 4 independent t-chains.
// ---------------------------------------------------------------------------
__global__ __launch_bounds__(256) void conv_ln_kernel(
    const __hip_bfloat16* __restrict__ y1p, const float* __restrict__ wT,
    const float* __restrict__ cb,
    const float* __restrict__ exg, const float* __restrict__ exb,
    const float* __restrict__ n2g, const float* __restrict__ n2b,
    _Float16* __restrict__ yb, __hip_bfloat16* __restrict__ h2) {
  const int tid = threadIdx.x;
  const int sp = blockIdx.x*16 + (tid >> 4);     // spatial site 0..16383
  const int cbase = (tid & 15) * 8;              // 8-channel group
  const int w = sp & 31, h = (sp >> 5) & 31, d = sp >> 10;
  const int psite = ((d+1)*PH + (h+1))*PW + (w+1);
  const short* base = (const short*)y1p + (size_t)psite*512 + cbase;

  float acc[4][8];
  {
    f32x4 cb0 = *(const f32x4*)&cb[cbase];
    f32x4 cb1 = *(const f32x4*)&cb[cbase + 4];
#pragma unroll
    for (int t = 0; t < 4; ++t) {
      acc[t][0]=cb0.x; acc[t][1]=cb0.y; acc[t][2]=cb0.z; acc[t][3]=cb0.w;
      acc[t][4]=cb1.x; acc[t][5]=cb1.y; acc[t][6]=cb1.z; acc[t][7]=cb1.w;
    }
  }

#pragma unroll
  for (int dd = -1; dd <= 1; ++dd)
#pragma unroll
    for (int dh = -1; dh <= 1; ++dh)
#pragma unroll
      for (int dw = -1; dw <= 1; ++dw) {
        const int tap = ((dd+1)*3 + (dh+1))*3 + (dw+1);
        const int toff = ((dd*PH + dh)*PW + dw)*512;
        f32x4 w0 = *(const f32x4*)&wT[tap*CC + cbase];
        f32x4 w1 = *(const f32x4*)&wT[tap*CC + cbase + 4];
#pragma unroll
        for (int t = 0; t < 4; ++t) {
          s16x8 v = *(const s16x8*)(base + toff + t*CC);
          acc[t][0] = fmaf(b2f(v[0]), w0.x, acc[t][0]);
          acc[t][1] = fmaf(b2f(v[1]), w0.y, acc[t][1]);
          acc[t][2] = fmaf(b2f(v[2]), w0.z, acc[t][2]);
          acc[t][3] = fmaf(b2f(v[3]), w0.w, acc[t][3]);
          acc[t][4] = fmaf(b2f(v[4]), w1.x, acc[t][4]);
          acc[t][5] = fmaf(b2f(v[5]), w1.y, acc[t][5]);
          acc[t][6] = fmaf(b2f(v[6]), w1.z, acc[t][6]);
          acc[t][7] = fmaf(b2f(v[7]), w1.w, acc[t][7]);
        }
      }

  f32x4 eg0 = *(const f32x4*)&exg[cbase], eg1 = *(const f32x4*)&exg[cbase+4];
  f32x4 eb0 = *(const f32x4*)&exb[cbase], eb1 = *(const f32x4*)&exb[cbase+4];
  f32x4 ng0 = *(const f32x4*)&n2g[cbase], ng1 = *(const f32x4*)&n2g[cbase+4];
  f32x4 nb0 = *(const f32x4*)&n2b[cbase], nb1 = *(const f32x4*)&n2b[cbase+4];
  float eg[8] = {eg0.x,eg0.y,eg0.z,eg0.w,eg1.x,eg1.y,eg1.z,eg1.w};
  float eb[8] = {eb0.x,eb0.y,eb0.z,eb0.w,eb1.x,eb1.y,eb1.z,eb1.w};
  float ng[8] = {ng0.x,ng0.y,ng0.z,ng0.w,ng1.x,ng1.y,ng1.z,ng1.w};
  float nb[8] = {nb0.x,nb0.y,nb0.z,nb0.w,nb1.x,nb1.y,nb1.z,nb1.w};

#pragma unroll
  for (int t = 0; t < 4; ++t) {
    float s = 0.f, sq = 0.f;
#pragma unroll
    for (int c = 0; c < 8; ++c) { s += acc[t][c]; sq = fmaf(acc[t][c], acc[t][c], sq); }
#pragma unroll
    for (int m = 1; m <= 8; m <<= 1) { s += __shfl_xor(s, m); sq += __shfl_xor(sq, m); }
    float mean = s * (1.f/128.f);
    float var  = sq * (1.f/128.f) - mean*mean;
    float rstd = rsqrtf(var + LNEPS);
    float y[8];
    f16x8 yo;
#pragma unroll
    for (int c = 0; c < 8; ++c) {
      y[c] = (acc[t][c] - mean)*rstd*eg[c] + eb[c];
      yo[c] = (_Float16)y[c];
    }
    *(f16x8*)&yb[(size_t)(sp*4 + t)*CC + cbase] = yo;
    float s2 = 0.f, sq2 = 0.f;
#pragma unroll
    for (int c = 0; c < 8; ++c) { s2 += y[c]; sq2 = fmaf(y[c], y[c], sq2); }
#pragma unroll
    for (int m = 1; m <= 8; m <<= 1) { s2 += __shfl_xor(s2, m); sq2 += __shfl_xor(sq2, m); }
    float mean2 = s2 * (1.f/128.f);
    float var2  = sq2 * (1.f/128.f) - mean2*mean2;
    float rstd2 = rsqrtf(var2 + LNEPS);
    s16x8 ho;
#pragma unroll
    for (int c = 0; c < 8; ++c)
      ho[c] = f2b((y[c] - mean2)*rstd2*ng[c] + nb[c]);
    *(s16x8*)&((short*)h2)[(size_t)(sp*4 + t)*CC + cbase] = ho;
  }
}

// ---------------------------------------------------------------------------
// Launch
// ---------------------------------------------------------------------------
extern "C" void kernel_launch(void* const* d_in, const int* in_sizes, int n_in,
                              void* d_out, int out_size, void* d_ws, size_t ws_size,
                              hipStream_t stream) {
  const float* x      = (const float*)d_in[0];
  const float* n1g    = (const float*)d_in[1];
  const float* n1b    = (const float*)d_in[2];
  const float* pos    = (const float*)d_in[3];
  const float* te     = (const float*)d_in[4];
  const float* qkv_w  = (const float*)d_in[5];
  const float* qkv_b  = (const float*)d_in[6];
  const float* proj_w = (const float*)d_in[7];
  const float* proj_b = (const float*)d_in[8];
  const float* conv_w = (const float*)d_in[9];
  const float* conv_b = (const float*)d_in[10];
  const float* exg    = (const float*)d_in[11];
  const float* exb    = (const float*)d_in[12];
  const float* n2g    = (const float*)d_in[13];
  const float* n2b    = (const float*)d_in[14];
  const float* fc1_w  = (const float*)d_in[15];
  const float* fc1_b  = (const float*)d_in[16];
  const float* fc2_w  = (const float*)d_in[17];
  const float* fc2_b  = (const float*)d_in[18];

  char* wsb = (char*)d_ws;
  __hip_bfloat16* wq  = (__hip_bfloat16*)(wsb);             // 384x128
  __hip_bfloat16* wp  = (__hip_bfloat16*)(wsb + 98304);     // 128x128
  __hip_bfloat16* w1  = (__hip_bfloat16*)(wsb + 131072);    // 512x128
  __hip_bfloat16* w2  = (__hip_bfloat16*)(wsb + 262144);    // 128x512
  float*          cwT = (float*)(wsb + 393216);             // 27x128

  const size_t A_OFF = (size_t)1 << 20;                     // 16 MiB region
  const size_t B_OFF = A_OFF + ((size_t)16 << 20);          // 48 MiB region
  const size_t C_OFF = B_OFF + ((size_t)48 << 20);          // 64 MiB region

  __hip_bfloat16* hbuf = (__hip_bfloat16*)(wsb + A_OFF);    // LN1 out
  __hip_bfloat16* obuf = (__hip_bfloat16*)(wsb + A_OFF);    // attn out (reuses A)
  __hip_bfloat16* h2in = (__hip_bfloat16*)(wsb + A_OFF);    // MLP in (reuses A)
  __hip_bfloat16* qkvb = (__hip_bfloat16*)(wsb + B_OFF);    // q|k|v, 16MiB each
  __hip_bfloat16* qb   = qkvb;
  __hip_bfloat16* kb   = qkvb + 8388608;
  __hip_bfloat16* vb   = qkvb + 16777216;
  __hip_bfloat16* y1p  = (__hip_bfloat16*)(wsb + B_OFF);    // padded proj out (20.3 MiB)
  _Float16* yb = (_Float16*)(wsb + B_OFF + ((size_t)24 << 20)); // fp16 y (16 MiB)
  __hip_bfloat16* gbuf = (__hip_bfloat16*)(wsb + C_OFF);    // GELU out (64 MiB)

  prep_kernel<<<782, 256, 0, stream>>>(qkv_w, proj_w, fc1_w, fc2_w, conv_w,
                                       wq, wp, w1, w2, cwT);
  ln1_pe_kernel<<<TOKS/8, 256, 0, stream>>>(x, n1g, n1b, pos, te, hbuf);
  gemm_kernel<0, 128><<<dim3(TOKS/128, 3), 256, 0, stream>>>(
      (const short*)hbuf, (const short*)wq, qkv_b, (void*)qkvb, nullptr);
  attn_mfma_kernel<<<NWIN*8, 256, 0, stream>>>(qb, kb, vb, obuf);
  border_zero_kernel<<<(PSITES*64 + 255)/256, 256, 0, stream>>>((short*)y1p);
  gemm_kernel<1, 128><<<dim3(TOKS/128, 1), 256, 0, stream>>>(
      (const short*)obuf, (const short*)wp, proj_b, (void*)y1p, nullptr);
  conv_ln_kernel<<<16384/16, 256, 0, stream>>>(y1p, cwT, conv_b,
      exg, exb, n2g, n2b, yb, h2in);
  gemm_kernel<2, 128><<<dim3(TOKS/128, 4), 256, 0, stream>>>(
      (const short*)h2in, (const short*)w1, fc1_b, (void*)gbuf, nullptr);
  gemm_kernel<3, 512><<<dim3(TOKS/128, 1), 256, 0, stream>>>(
      (const short*)gbuf, (const short*)w2, fc2_b, (void*)d_out, yb);
}

// Round 19
// 169.347 us; speedup vs baseline: 1.3478x; 1.0113x over previous
//
#include <hip/hip_runtime.h>
#include <hip/hip_bf16.h>

// ---------------------------------------------------------------------------
// CrossFormerBlock on MI355X (gfx950)
// B=1 D=16 H=32 W=32 T=4 C=128, G=4, NH=8, HD=16, NW=256 windows, N=256 tok/win
// R19 (from R18 best=171.3us):
//  (1) conv 2-t-chain variant: VGPR <=64 -> 32 waves/CU (R8's 4-chain @VGPR 92
//      capped at 16) with ~6 loads in flight/thread — more latency hiding.
//  (2) fc2 2-phase LDS double-buffer (T3-min template): fc2 grid = 2 blocks/CU
//      and 64KB dbuf allows exactly 2/CU -> zero occupancy cost, 8 K-tiles
//      gain stage/compute overlap.
//  (3) prep+ln1 merged into one setup kernel (one fewer launch gap).
// ---------------------------------------------------------------------------

typedef __attribute__((ext_vector_type(8))) short  s16x8;
typedef __attribute__((ext_vector_type(4))) short  s16x4;
typedef __attribute__((ext_vector_type(4))) float  f32x4;
typedef __attribute__((ext_vector_type(8))) _Float16 f16x8;
typedef __attribute__((ext_vector_type(4))) _Float16 f16x4;

#define CC    128
#define NWIN  256
#define TOKS  65536            // total tokens = D*H*W*T
#define SCALE 0.25f
#define LNEPS 1e-5f
// padded spatial geometry for conv
#define PD 18
#define PH 34
#define PW 34
#define PSITES (PD*PH*PW)                // 20808
#define Y1P_SHORTS ((size_t)PSITES*512)  // *4t*128c
#define PREP_BLOCKS 782                  // covers 196608+3456 elements

__device__ __forceinline__ float b2f(short s) {
  union { unsigned u; float f; } c; c.u = ((unsigned)(unsigned short)s) << 16; return c.f;
}
__device__ __forceinline__ short f2b(float f) {
  __hip_bfloat16 h = __float2bfloat16(f);
  return *reinterpret_cast<short*>(&h);
}
__device__ __forceinline__ float fast_gelu(float x) {
  float u = 1.595769122f * x * fmaf(0.044715f, x*x, 1.0f);
  return x / (1.0f + __expf(-u));
}

__device__ __forceinline__ f32x4 mfma16x16x16_bf16(s16x4 a, s16x4 b, f32x4 c) {
#if __has_builtin(__builtin_amdgcn_mfma_f32_16x16x16_bf16)
  return __builtin_amdgcn_mfma_f32_16x16x16_bf16(a, b, c, 0, 0, 0);
#elif __has_builtin(__builtin_amdgcn_mfma_f32_16x16x16bf16_1k)
  return __builtin_amdgcn_mfma_f32_16x16x16bf16_1k(a, b, c, 0, 0, 0);
#else
  f32x4 d;
  asm("v_mfma_f32_16x16x16_bf16 %0, %1, %2, %3" : "=v"(d) : "v"(a), "v"(b), "v"(c));
  return d;
#endif
}

// async global->LDS, 16B per lane; lds base wave-uniform (HW appends lane*16).
__device__ __forceinline__ void gload16(const short* g, short* l) {
  __builtin_amdgcn_global_load_lds(
      (const __attribute__((address_space(1))) void*)g,
      (__attribute__((address_space(3))) void*)l, 16, 0, 0);
}

// ---------------------------------------------------------------------------
// Kernel: SETUP = weight prep (blocks 0..781) + LN1+PE (blocks 782..8973)
// ---------------------------------------------------------------------------
__global__ __launch_bounds__(256) void setup_kernel(
    const float* __restrict__ qkv_w, const float* __restrict__ proj_w,
    const float* __restrict__ fc1_w, const float* __restrict__ fc2_w,
    const float* __restrict__ conv_w,
    __hip_bfloat16* wq, __hip_bfloat16* wp,
    __hip_bfloat16* w1, __hip_bfloat16* w2, float* cwT,
    const float* __restrict__ x, const float* __restrict__ g,
    const float* __restrict__ b, const float* __restrict__ pos,
    const float* __restrict__ te, __hip_bfloat16* __restrict__ hb) {
  if (blockIdx.x < PREP_BLOCKS) {
    int idx = blockIdx.x * 256 + threadIdx.x;
    if (idx < 49152) {
      wq[idx] = __float2bfloat16(qkv_w[idx]);
    } else if (idx < 65536) {
      wp[idx - 49152] = __float2bfloat16(proj_w[idx - 49152]);
    } else if (idx < 131072) {
      w1[idx - 65536] = __float2bfloat16(fc1_w[idx - 65536]);
    } else if (idx < 196608) {
      w2[idx - 131072] = __float2bfloat16(fc2_w[idx - 131072]);
    } else if (idx < 196608 + 27*128) {
      int j = idx - 196608;
      int tap = j >> 7, c = j & 127;
      cwT[tap*128 + c] = conv_w[c*27 + tap];   // (C,1,3,3,3) -> (27,C)
    }
    return;
  }
  // ---- LN1 + PE: 32 lanes/token, f32x4 loads ----
  const int tid = threadIdx.x;
  const int tk = (blockIdx.x - PREP_BLOCKS)*8 + (tid >> 5);
  const int c4 = (tid & 31) * 4;
  const int wid = tk >> 8, n = tk & 255;
  const int t = n >> 6, gd = (n >> 4) & 3, gh = (n >> 2) & 3, gw = n & 3;
  const int wd = wid >> 6, wh = (wid >> 3) & 7, ww = wid & 7;
  const int d = wd*4 + gd, h = wh*4 + gh, w = ww*4 + gw;
  const size_t xoff = ((size_t)((d*32 + h)*32 + w)*4 + t) * CC;
  f32x4 v = *(const f32x4*)&x[xoff + c4];
  float s  = (v.x + v.y) + (v.z + v.w);
  float sq = (v.x*v.x + v.y*v.y) + (v.z*v.z + v.w*v.w);
#pragma unroll
  for (int m = 1; m <= 16; m <<= 1) { s += __shfl_xor(s, m); sq += __shfl_xor(sq, m); }
  const float mean = s * (1.f/128.f);
  const float var  = sq * (1.f/128.f) - mean*mean;
  const float rstd = rsqrtf(var + LNEPS);
  const int pb = ((gd*4 + gh)*4 + gw) * CC, tb = t * CC;
  f32x4 gv = *(const f32x4*)&g[c4];
  f32x4 bv = *(const f32x4*)&b[c4];
  f32x4 pv = *(const f32x4*)&pos[pb + c4];
  f32x4 tv = *(const f32x4*)&te[tb + c4];
  s16x4 o;
  o[0] = f2b((v.x - mean)*rstd*gv.x + bv.x + pv.x + tv.x);
  o[1] = f2b((v.y - mean)*rstd*gv.y + bv.y + pv.y + tv.y);
  o[2] = f2b((v.z - mean)*rstd*gv.z + bv.z + pv.z + tv.z);
  o[3] = f2b((v.w - mean)*rstd*gv.w + bv.w + pv.w + tv.w);
  *(s16x4*)&((short*)hb)[(size_t)tk*CC + c4] = o;
}

// ---------------------------------------------------------------------------
// Kernel: zero only the BORDER sites of the padded y1 buffer (4424 sites).
// ---------------------------------------------------------------------------
__global__ __launch_bounds__(256) void border_zero_kernel(short* __restrict__ y1p) {
  int idx = blockIdx.x*256 + threadIdx.x;
  if (idx >= PSITES*64) return;
  int site = idx >> 6;
  int w = site % PW, hh = (site / PW) % PH, d = site / (PW*PH);
  if (d != 0 && d != PD-1 && hh != 0 && hh != PH-1 && w != 0 && w != PW-1) return;
  *(s16x8*)&y1p[(size_t)site*512 + (idx & 63)*8] = (s16x8)0;
}

// ---------------------------------------------------------------------------
// GEMM template: 128x128 tile, BK=64, 4 waves, compile-time K (KK).
// Staging: global_load_lds width=16, LINEAR LDS [128][64].
// DB=1 (fc2): 2-phase double-buffer — stage(t+1) issued async BEFORE
// compute(t); single drain+barrier per tile (T3-minimum template).
// MODE 0: qkv split; MODE 1: proj -> PADDED spatial scatter bf16;
// MODE 2: fc1 + fast GELU; MODE 3: fc2 + bias + fp16 residual -> fp32 d_out
// ---------------------------------------------------------------------------
template <int MODE, int KK, int DB>
__global__ __launch_bounds__(256) void gemm_kernel(
    const short* __restrict__ Ag, const short* __restrict__ Wg,
    const float* __restrict__ bias,
    void* __restrict__ out0, const _Float16* __restrict__ resid) {
  __shared__ __align__(16) short As[DB + 1][128*64];
  __shared__ __align__(16) short Bs[DB + 1][128*64];
  const int tid = threadIdx.x;
  const int m0 = blockIdx.x * 128;
  const int n0 = blockIdx.y * 128;
  const int lane = tid & 63, wv = tid >> 6;
  const int wr = wv >> 1, wc = wv & 1;
  const int fr = lane & 15, kg = lane >> 4;

  f32x4 acc[4][4];
#pragma unroll
  for (int i = 0; i < 4; ++i)
#pragma unroll
    for (int j = 0; j < 4; ++j) acc[i][j] = (f32x4)0.f;

  if constexpr (DB == 0) {
#pragma unroll
    for (int kc = 0; kc < KK; kc += 64) {
      __syncthreads();
#pragma unroll
      for (int i = 0; i < 4; ++i) {
        const int e = i*2048 + tid*8;
        const int row = e >> 6, col = e & 63;
        gload16(Ag + (size_t)(m0 + row)*KK + kc + col, &As[0][i*2048 + wv*512]);
        gload16(Wg + (size_t)(n0 + row)*KK + kc + col, &Bs[0][i*2048 + wv*512]);
      }
      __syncthreads();
#pragma unroll
      for (int ks = 0; ks < 2; ++ks) {
        s16x8 a[4], b[4];
#pragma unroll
        for (int i = 0; i < 4; ++i)
          a[i] = *(const s16x8*)&As[0][(wr*64 + i*16 + fr)*64 + ks*32 + kg*8];
#pragma unroll
        for (int j = 0; j < 4; ++j)
          b[j] = *(const s16x8*)&Bs[0][(wc*64 + j*16 + fr)*64 + ks*32 + kg*8];
#pragma unroll
        for (int i = 0; i < 4; ++i)
#pragma unroll
          for (int j = 0; j < 4; ++j)
            acc[i][j] = __builtin_amdgcn_mfma_f32_16x16x32_bf16(b[j], a[i], acc[i][j], 0, 0, 0);
      }
    }
  } else {
    // 2-phase pipeline: prologue stages tile 0; each iter issues tile t+1
    // async, computes tile t, then one drain+barrier.
    constexpr int NT = KK / 64;
#pragma unroll
    for (int i = 0; i < 4; ++i) {
      const int e = i*2048 + tid*8;
      const int row = e >> 6, col = e & 63;
      gload16(Ag + (size_t)(m0 + row)*KK + col, &As[0][i*2048 + wv*512]);
      gload16(Wg + (size_t)(n0 + row)*KK + col, &Bs[0][i*2048 + wv*512]);
    }
    __syncthreads();
#pragma unroll
    for (int t = 0; t < NT; ++t) {
      const int cur = t & 1;
      if (t + 1 < NT) {
        const int kc = (t + 1) * 64;
#pragma unroll
        for (int i = 0; i < 4; ++i) {
          const int e = i*2048 + tid*8;
          const int row = e >> 6, col = e & 63;
          gload16(Ag + (size_t)(m0 + row)*KK + kc + col, &As[cur^1][i*2048 + wv*512]);
          gload16(Wg + (size_t)(n0 + row)*KK + kc + col, &Bs[cur^1][i*2048 + wv*512]);
        }
      }
#pragma unroll
      for (int ks = 0; ks < 2; ++ks) {
        s16x8 a[4], b[4];
#pragma unroll
        for (int i = 0; i < 4; ++i)
          a[i] = *(const s16x8*)&As[cur][(wr*64 + i*16 + fr)*64 + ks*32 + kg*8];
#pragma unroll
        for (int j = 0; j < 4; ++j)
          b[j] = *(const s16x8*)&Bs[cur][(wc*64 + j*16 + fr)*64 + ks*32 + kg*8];
#pragma unroll
        for (int i = 0; i < 4; ++i)
#pragma unroll
          for (int j = 0; j < 4; ++j)
            acc[i][j] = __builtin_amdgcn_mfma_f32_16x16x32_bf16(b[j], a[i], acc[i][j], 0, 0, 0);
      }
      __syncthreads();
    }
  }

  const int nbb = n0 + wc*64 + kg*4;
  f32x4 bj4[4];
#pragma unroll
  for (int j = 0; j < 4; ++j) bj4[j] = *(const f32x4*)&bias[nbb + j*16];

#pragma unroll
  for (int i = 0; i < 4; ++i) {
    const int m = m0 + wr*64 + i*16 + fr;
    if constexpr (MODE == 0) {
      short* qs = (short*)out0;
      const int sec = n0 >> 7;
      const float scl = (sec == 0) ? SCALE : 1.0f;
      const int wid = m >> 8, ntok = m & 255;
      const int rowbase = sec*8388608 + (wid*8)*4096 + ntok*16 + (nbb & 15);
#pragma unroll
      for (int j = 0; j < 4; ++j) {
        const int head = ((nbb + j*16) >> 4) & 7;
        f32x4 v = acc[i][j];
        s16x4 o;
        o[0] = f2b(fmaf(v[0], scl, bj4[j].x*scl));
        o[1] = f2b(fmaf(v[1], scl, bj4[j].y*scl));
        o[2] = f2b(fmaf(v[2], scl, bj4[j].z*scl));
        o[3] = f2b(fmaf(v[3], scl, bj4[j].w*scl));
        *(s16x4*)&qs[rowbase + head*4096] = o;
      }
    } else if constexpr (MODE == 1) {
      short* y1o = (short*)out0;       // PADDED [18][34][34][4][128]
      const int wid = m >> 8, ntok = m & 255;
      const int t = ntok >> 6, gd = (ntok >> 4) & 3, gh = (ntok >> 2) & 3, gw = ntok & 3;
      const int wd = wid >> 6, wh = (wid >> 3) & 7, ww = wid & 7;
      const int sr = (((wd*4 + gd + 1)*PH + wh*4 + gh + 1)*PW + ww*4 + gw + 1)*4 + t;
      const int base = sr*CC + nbb;
#pragma unroll
      for (int j = 0; j < 4; ++j) {
        f32x4 v = acc[i][j];
        s16x4 o;
        o[0] = f2b(v[0] + bj4[j].x); o[1] = f2b(v[1] + bj4[j].y);
        o[2] = f2b(v[2] + bj4[j].z); o[3] = f2b(v[3] + bj4[j].w);
        *(s16x4*)&y1o[base + j*16] = o;
      }
    } else if constexpr (MODE == 2) {
      short* gp = (short*)out0;
      const int base = m*512 + nbb;
#pragma unroll
      for (int j = 0; j < 4; ++j) {
        f32x4 v = acc[i][j];
        s16x4 o;
        o[0] = f2b(fast_gelu(v[0] + bj4[j].x)); o[1] = f2b(fast_gelu(v[1] + bj4[j].y));
        o[2] = f2b(fast_gelu(v[2] + bj4[j].z)); o[3] = f2b(fast_gelu(v[3] + bj4[j].w));
        *(s16x4*)&gp[base + j*16] = o;
      }
    } else {
      float* outp = (float*)out0;
      const int base = m*CC + nbb;
#pragma unroll
      for (int j = 0; j < 4; ++j) {
        f32x4 v = acc[i][j];
        f16x4 rz = *(const f16x4*)&resid[base + j*16];
        f32x4 o;
        o.x = v[0] + bj4[j].x + (float)rz[0]; o.y = v[1] + bj4[j].y + (float)rz[1];
        o.z = v[2] + bj4[j].z + (float)rz[2]; o.w = v[3] + bj4[j].w + (float)rz[3];
        *(f32x4*)&outp[base + j*16] = o;
      }
    }
  }
}

// ---------------------------------------------------------------------------
// Kernel: MFMA window attention (unchanged from R2).
// ---------------------------------------------------------------------------
#define KPAD 20
#define VPAD 264
__global__ __launch_bounds__(256) void attn_mfma_kernel(
    const __hip_bfloat16* __restrict__ qb, const __hip_bfloat16* __restrict__ kb,
    const __hip_bfloat16* __restrict__ vb, __hip_bfloat16* __restrict__ ob) {
  __shared__ __align__(16) short kL[256*KPAD];
  __shared__ __align__(16) short vT[16*VPAD];
  const int bh = blockIdx.x;                // win*8 + head
  const int wid = bh >> 3, head = bh & 7;
  const int tid = threadIdx.x;
  const short* kg = (const short*)kb + (size_t)bh*4096;
  const short* vg = (const short*)vb + (size_t)bh*4096;
  const short* qg = (const short*)qb + (size_t)bh*4096;
  {
    s16x8 a0 = *(const s16x8*)&kg[tid*16];
    s16x8 a1 = *(const s16x8*)&kg[tid*16 + 8];
    *(s16x8*)&kL[tid*KPAD]     = a0;
    *(s16x8*)&kL[tid*KPAD + 8] = a1;
    s16x8 b0 = *(const s16x8*)&vg[tid*16];
    s16x8 b1 = *(const s16x8*)&vg[tid*16 + 8];
#pragma unroll
    for (int d = 0; d < 8; ++d) {
      vT[d*VPAD + tid]     = b0[d];
      vT[(d+8)*VPAD + tid] = b1[d];
    }
  }
  __syncthreads();
  const int wv = tid >> 6, lane = tid & 63;
  const int fr = lane & 15, hi = lane >> 4;
  s16x4 kfrag[16], vfrag[16];
#pragma unroll
  for (int t = 0; t < 16; ++t) {
    kfrag[t] = *(const s16x4*)&kL[(t*16 + fr)*KPAD + hi*4];
    vfrag[t] = *(const s16x4*)&vT[fr*VPAD + t*16 + hi*4];
  }
  short* obs = (short*)ob;
  for (int qt = 0; qt < 4; ++qt) {
    const int q0 = wv*64 + qt*16;
    s16x4 qfrag = *(const s16x4*)&qg[(q0 + fr)*16 + hi*4];
    f32x4 st[16];
#pragma unroll
    for (int kt = 0; kt < 16; ++kt)
      st[kt] = mfma16x16x16_bf16(kfrag[kt], qfrag, (f32x4)0.f);
    float den = 0.f;
    f32x4 oacc = (f32x4)0.f;
#pragma unroll
    for (int kt = 0; kt < 16; ++kt) {
      float e0 = __expf(st[kt][0]), e1 = __expf(st[kt][1]);
      float e2 = __expf(st[kt][2]), e3 = __expf(st[kt][3]);
      den += (e0 + e1) + (e2 + e3);
      s16x4 pa;
      pa[0] = f2b(e0); pa[1] = f2b(e1); pa[2] = f2b(e2); pa[3] = f2b(e3);
      oacc = mfma16x16x16_bf16(vfrag[kt], pa, oacc);
    }
    den += __shfl_xor(den, 16);
    den += __shfl_xor(den, 32);
    float inv = 1.f / den;
    s16x4 ov;
    ov[0] = f2b(oacc[0]*inv); ov[1] = f2b(oacc[1]*inv);
    ov[2] = f2b(oacc[2]*inv); ov[3] = f2b(oacc[3]*inv);
    *(s16x4*)&obs[((size_t)wid*256 + q0 + fr)*CC + head*16 + hi*4] = ov;
  }
}

// ---------------------------------------------------------------------------
// Kernel: FUSED conv3x3x3 (padded bf16 in, NO guards) + exln + norm2.
// R19: 2-t-chain variant — thread = (site, t-pair, c8). 2 chains keep VGPR
// <=64 -> 32 waves/CU (R8's 4-chain @92 VGPR capped at 16). Same per-element
// math/order -> bit-identical output. Grid 2048 blocks (8 sites/block).
// ---------------------------------------------------------------------------
__global__ __launch_bounds__(256) void conv_ln_kernel(
    const __hip_bfloat16* __restrict__ y1p, const float* __restrict__ wT,
    const float* __restrict__ cb,
    const float* __restrict__ exg, const float* __restrict__ exb,
    const float* __restrict__ n2g, const float* __restrict__ n2b,
    _Float16* __restrict__ yb, __hip_bfloat16* __restrict__ h2) {
  const int tid = threadIdx.x;
  const int sp = blockIdx.x*8 + (tid >> 5);      // spatial site 0..16383
  const int tp = (tid >> 4) & 1;                 // t-pair: tokens tp*2, tp*2+1
  const int cbase = (tid & 15) * 8;              // 8-channel group
  const int w = sp & 31, h = (sp >> 5) & 31, d = sp >> 10;
  const int psite = ((d+1)*PH + (h+1))*PW + (w+1);
  const short* base = (const short*)y1p + (size_t)psite*512 + tp*2*CC + cbase;

  float acc[2][8];
  {
    f32x4 cb0 = *(const f32x4*)&cb[cbase];
    f32x4 cb1 = *(const f32x4*)&cb[cbase + 4];
#pragma unroll
    for (int t = 0; t < 2; ++t) {
      acc[t][0]=cb0.x; acc[t][1]=cb0.y; acc[t][2]=cb0.z; acc[t][3]=cb0.w;
      acc[t][4]=cb1.x; acc[t][5]=cb1.y; acc[t][6]=cb1.z; acc[t][7]=cb1.w;
    }
  }

#pragma unroll
  for (int dd = -1; dd <= 1; ++dd)
#pragma unroll
    for (int dh = -1; dh <= 1; ++dh)
#pragma unroll
      for (int dw = -1; dw <= 1; ++dw) {
        const int tap = ((dd+1)*3 + (dh+1))*3 + (dw+1);
        const int toff = ((dd*PH + dh)*PW + dw)*512;
        f32x4 w0 = *(const f32x4*)&wT[tap*CC + cbase];
        f32x4 w1 = *(const f32x4*)&wT[tap*CC + cbase + 4];
#pragma unroll
        for (int t = 0; t < 2; ++t) {
          s16x8 v = *(const s16x8*)(base + toff + t*CC);
          acc[t][0] = fmaf(b2f(v[0]), w0.x, acc[t][0]);
          acc[t][1] = fmaf(b2f(v[1]), w0.y, acc[t][1]);
          acc[t][2] = fmaf(b2f(v[2]), w0.z, acc[t][2]);
          acc[t][3] = fmaf(b2f(v[3]), w0.w, acc[t][3]);
          acc[t][4] = fmaf(b2f(v[4]), w1.x, acc[t][4]);
          acc[t][5] = fmaf(b2f(v[5]), w1.y, acc[t][5]);
          acc[t][6] = fmaf(b2f(v[6]), w1.z, acc[t][6]);
          acc[t][7] = fmaf(b2f(v[7]), w1.w, acc[t][7]);
        }
      }

  f32x4 eg0 = *(const f32x4*)&exg[cbase], eg1 = *(const f32x4*)&exg[cbase+4];
  f32x4 eb0 = *(const f32x4*)&exb[cbase], eb1 = *(const f32x4*)&exb[cbase+4];
  f32x4 ng0 = *(const f32x4*)&n2g[cbase], ng1 = *(const f32x4*)&n2g[cbase+4];
  f32x4 nb0 = *(const f32x4*)&n2b[cbase], nb1 = *(const f32x4*)&n2b[cbase+4];
  float eg[8] = {eg0.x,eg0.y,eg0.z,eg0.w,eg1.x,eg1.y,eg1.z,eg1.w};
  float eb[8] = {eb0.x,eb0.y,eb0.z,eb0.w,eb1.x,eb1.y,eb1.z,eb1.w};
  float ng[8] = {ng0.x,ng0.y,ng0.z,ng0.w,ng1.x,ng1.y,ng1.z,ng1.w};
  float nb[8] = {nb0.x,nb0.y,nb0.z,nb0.w,nb1.x,nb1.y,nb1.z,nb1.w};

#pragma unroll
  for (int t = 0; t < 2; ++t) {
    float s = 0.f, sq = 0.f;
#pragma unroll
    for (int c = 0; c < 8; ++c) { s += acc[t][c]; sq = fmaf(acc[t][c], acc[t][c], sq); }
#pragma unroll
    for (int m = 1; m <= 8; m <<= 1) { s += __shfl_xor(s, m); sq += __shfl_xor(sq, m); }
    float mean = s * (1.f/128.f);
    float var  = sq * (1.f/128.f) - mean*mean;
    float rstd = rsqrtf(var + LNEPS);
    float y[8];
    f16x8 yo;
#pragma unroll
    for (int c = 0; c < 8; ++c) {
      y[c] = (acc[t][c] - mean)*rstd*eg[c] + eb[c];
      yo[c] = (_Float16)y[c];
    }
    const int tok = sp*4 + tp*2 + t;
    *(f16x8*)&yb[(size_t)tok*CC + cbase] = yo;
    float s2 = 0.f, sq2 = 0.f;
#pragma unroll
    for (int c = 0; c < 8; ++c) { s2 += y[c]; sq2 = fmaf(y[c], y[c], sq2); }
#pragma unroll
    for (int m = 1; m <= 8; m <<= 1) { s2 += __shfl_xor(s2, m); sq2 += __shfl_xor(sq2, m); }
    float mean2 = s2 * (1.f/128.f);
    float var2  = sq2 * (1.f/128.f) - mean2*mean2;
    float rstd2 = rsqrtf(var2 + LNEPS);
    s16x8 ho;
#pragma unroll
    for (int c = 0; c < 8; ++c)
      ho[c] = f2b((y[c] - mean2)*rstd2*ng[c] + nb[c]);
    *(s16x8*)&((short*)h2)[(size_t)tok*CC + cbase] = ho;
  }
}

// ---------------------------------------------------------------------------
// Launch
// ---------------------------------------------------------------------------
extern "C" void kernel_launch(void* const* d_in, const int* in_sizes, int n_in,
                              void* d_out, int out_size, void* d_ws, size_t ws_size,
                              hipStream_t stream) {
  const float* x      = (const float*)d_in[0];
  const float* n1g    = (const float*)d_in[1];
  const float* n1b    = (const float*)d_in[2];
  const float* pos    = (const float*)d_in[3];
  const float* te     = (const float*)d_in[4];
  const float* qkv_w  = (const float*)d_in[5];
  const float* qkv_b  = (const float*)d_in[6];
  const float* proj_w = (const float*)d_in[7];
  const float* proj_b = (const float*)d_in[8];
  const float* conv_w = (const float*)d_in[9];
  const float* conv_b = (const float*)d_in[10];
  const float* exg    = (const float*)d_in[11];
  const float* exb    = (const float*)d_in[12];
  const float* n2g    = (const float*)d_in[13];
  const float* n2b    = (const float*)d_in[14];
  const float* fc1_w  = (const float*)d_in[15];
  const float* fc1_b  = (const float*)d_in[16];
  const float* fc2_w  = (const float*)d_in[17];
  const float* fc2_b  = (const float*)d_in[18];

  char* wsb = (char*)d_ws;
  __hip_bfloat16* wq  = (__hip_bfloat16*)(wsb);             // 384x128
  __hip_bfloat16* wp  = (__hip_bfloat16*)(wsb + 98304);     // 128x128
  __hip_bfloat16* w1  = (__hip_bfloat16*)(wsb + 131072);    // 512x128
  __hip_bfloat16* w2  = (__hip_bfloat16*)(wsb + 262144);    // 128x512
  float*          cwT = (float*)(wsb + 393216);             // 27x128

  const size_t A_OFF = (size_t)1 << 20;                     // 16 MiB region
  const size_t B_OFF = A_OFF + ((size_t)16 << 20);          // 48 MiB region
  const size_t C_OFF = B_OFF + ((size_t)48 << 20);          // 64 MiB region

  __hip_bfloat16* hbuf = (__hip_bfloat16*)(wsb + A_OFF);    // LN1 out
  __hip_bfloat16* obuf = (__hip_bfloat16*)(wsb + A_OFF);    // attn out (reuses A)
  __hip_bfloat16* h2in = (__hip_bfloat16*)(wsb + A_OFF);    // MLP in (reuses A)
  __hip_bfloat16* qkvb = (__hip_bfloat16*)(wsb + B_OFF);    // q|k|v, 16MiB each
  __hip_bfloat16* qb   = qkvb;
  __hip_bfloat16* kb   = qkvb + 8388608;
  __hip_bfloat16* vb   = qkvb + 16777216;
  __hip_bfloat16* y1p  = (__hip_bfloat16*)(wsb + B_OFF);    // padded proj out (20.3 MiB)
  _Float16* yb = (_Float16*)(wsb + B_OFF + ((size_t)24 << 20)); // fp16 y (16 MiB)
  __hip_bfloat16* gbuf = (__hip_bfloat16*)(wsb + C_OFF);    // GELU out (64 MiB)

  setup_kernel<<<PREP_BLOCKS + TOKS/8, 256, 0, stream>>>(
      qkv_w, proj_w, fc1_w, fc2_w, conv_w, wq, wp, w1, w2, cwT,
      x, n1g, n1b, pos, te, hbuf);
  gemm_kernel<0, 128, 0><<<dim3(TOKS/128, 3), 256, 0, stream>>>(
      (const short*)hbuf, (const short*)wq, qkv_b, (void*)qkvb, nullptr);
  attn_mfma_kernel<<<NWIN*8, 256, 0, stream>>>(qb, kb, vb, obuf);
  border_zero_kernel<<<(PSITES*64 + 255)/256, 256, 0, stream>>>((short*)y1p);
  gemm_kernel<1, 128, 0><<<dim3(TOKS/128, 1), 256, 0, stream>>>(
      (const short*)obuf, (const short*)wp, proj_b, (void*)y1p, nullptr);
  conv_ln_kernel<<<16384/8, 256, 0, stream>>>(y1p, cwT, conv_b,
      exg, exb, n2g, n2b, yb, h2in);
  gemm_kernel<2, 128, 0><<<dim3(TOKS/128, 4), 256, 0, stream>>>(
      (const short*)h2in, (const short*)w1, fc1_b, (void*)gbuf, nullptr);
  gemm_kernel<3, 512, 1><<<dim3(TOKS/128, 1), 256, 0, stream>>>(
      (const short*)gbuf, (const short*)w2, fc2_b, (void*)d_out, yb);
}